// Round 3
// baseline (513.311 us; speedup 1.0000x reference)
//
#include <hip/hip_runtime.h>
#include <hip/hip_bf16.h>

#define C_ 256
#define N_ 4096
#define CN (C_*N_)
#define EPSF 1e-5f
#define NS_ITERS 6
#define KSPLIT 16  // split-K for MFMA cov partials
#define LSTR 40   // LDS row stride in ushort for covmm (80 B)
#define GSTR 72   // gram LDS row stride in ushort: 144 B -> bank-class step 9==1 mod 8
                  // => consecutive-8-lane groups conflict-free on staged writes AND frag reads

typedef _Float16 f16x8 __attribute__((ext_vector_type(8)));
typedef float f32x4 __attribute__((ext_vector_type(4)));

__device__ __forceinline__ int refl(int t) {
  return t < 0 ? -t : (t > 63 ? 126 - t : t);
}

// fp16 2-way split: v = h + l exact to ~2^-22 rel. Products hh+hl+lh drop only ll
// ~2^-22 rel — below the fp32 reference's own accumulation noise.
__device__ __forceinline__ unsigned short f2h(float x) {
  _Float16 h = (_Float16)x;
  return __builtin_bit_cast(unsigned short, h);
}
__device__ __forceinline__ float h2f(unsigned short u) {
  return (float)__builtin_bit_cast(_Float16, u);
}

__device__ __forceinline__ void fma16(float acc[4][4], float a0, float a1, float a2, float a3, float4 b) {
  acc[0][0] += a0*b.x; acc[0][1] += a0*b.y; acc[0][2] += a0*b.z; acc[0][3] += a0*b.w;
  acc[1][0] += a1*b.x; acc[1][1] += a1*b.y; acc[1][2] += a1*b.z; acc[1][3] += a1*b.w;
  acc[2][0] += a2*b.x; acc[2][1] += a2*b.y; acc[2][2] += a2*b.z; acc[2][3] += a2*b.w;
  acc[3][0] += a3*b.x; acc[3][1] += a3*b.y; acc[3][2] += a3*b.z; acc[3][3] += a3*b.w;
}

// ---------------- means ----------------
__global__ __launch_bounds__(256) void k_mean(const float* content, const float* style,
                                              float* means) {
  int c = blockIdx.x, m = blockIdx.y, t = threadIdx.x;
  const float* x = (m < 2 ? content : style) + (size_t)(m & 1) * CN + (size_t)c * N_;
  float s = 0.f;
  for (int i = t; i < N_; i += 256) s += x[i];
  __shared__ float red[256];
  red[t] = s; __syncthreads();
  for (int off = 128; off > 0; off >>= 1) { if (t < off) red[t] += red[t + off]; __syncthreads(); }
  if (t == 0) means[m * C_ + c] = red[0] * (1.f / N_);
}

// ---------------- 2-way fp16 split of raw content/style for MFMA cov ----------------
__global__ __launch_bounds__(256) void k_splitcov(const float* content, const float* style,
                                                  unsigned short* sp) {
  int m = blockIdx.y;
  const float* x = (m < 2 ? content : style) + (size_t)(m & 1) * CN;
  size_t base = (size_t)m * 2 * (size_t)CN;
  size_t i = ((size_t)blockIdx.x * 256 + threadIdx.x) * 4;
  float4 v = *(const float4*)&x[i];
  float vv[4] = {v.x, v.y, v.z, v.w};
  unsigned short h[4], lo[4];
#pragma unroll
  for (int j = 0; j < 4; j++) {
    unsigned short hh = f2h(vv[j]);
    float r1 = vv[j] - h2f(hh);
    h[j] = hh; lo[j] = f2h(r1);
  }
  *(ushort4*)&sp[base + i]      = make_ushort4(h[0], h[1], h[2], h[3]);
  *(ushort4*)&sp[base + CN + i] = make_ushort4(lo[0], lo[1], lo[2], lo[3]);
}

// ---------------- covariance raw sums via 3-term fp16 MFMA, split-K ----------------
__global__ __launch_bounds__(512) void k_covmm(const unsigned short* sp, float* covp) {
  __shared__ unsigned short sm[4*128*LSTR];   // 40960 B
  const int P = 128*LSTR;
  int t = threadIdx.x;
  int kc = blockIdx.x, m = blockIdx.z;
  int ti = blockIdx.y >> 1, tj = blockIdx.y & 1;
  const unsigned short* Xh = sp + (size_t)m * 2 * (size_t)CN;
  const unsigned short* Xl = Xh + CN;
  int v0 = ti * 128, u0 = tj * 128;
  int wave = t >> 6, lane = t & 63;
  int wv = wave >> 1, wu = wave & 1;
  int lx16 = lane & 15, quad = lane >> 4;
  int srow = t >> 2, sseg = (t & 3) * 8;
  f32x4 acc[2][4];
#pragma unroll
  for (int i = 0; i < 2; i++)
#pragma unroll
    for (int j = 0; j < 4; j++) acc[i][j] = (f32x4){0.f, 0.f, 0.f, 0.f};

  int kbeg = kc * (N_ / KSPLIT), kend = kbeg + (N_ / KSPLIT);
  for (int k0 = kbeg; k0 < kend; k0 += 32) {
    __syncthreads();
    {
      size_t goA = (size_t)(v0 + srow) * N_ + k0 + sseg;
      size_t goB = (size_t)(u0 + srow) * N_ + k0 + sseg;
      int lo_ = srow * LSTR + sseg;
      *(float4*)&sm[0*P + lo_] = *(const float4*)&Xh[goA];
      *(float4*)&sm[1*P + lo_] = *(const float4*)&Xl[goA];
      *(float4*)&sm[2*P + lo_] = *(const float4*)&Xh[goB];
      *(float4*)&sm[3*P + lo_] = *(const float4*)&Xl[goB];
    }
    __syncthreads();
#pragma unroll
    for (int mt = 0; mt < 2; mt++) {
      int arow = (wv*32 + mt*16 + lx16)*LSTR + quad*8;
      f16x8 ah = *(const f16x8*)&sm[0*P + arow];
      f16x8 al = *(const f16x8*)&sm[1*P + arow];
#pragma unroll
      for (int nt = 0; nt < 4; nt++) {
        int brow = (wu*64 + nt*16 + lx16)*LSTR + quad*8;
        f16x8 bh = *(const f16x8*)&sm[2*P + brow];
        f16x8 bl = *(const f16x8*)&sm[3*P + brow];
        f32x4 a = acc[mt][nt];
        a = __builtin_amdgcn_mfma_f32_16x16x32_f16(ah, bh, a, 0, 0, 0);
        a = __builtin_amdgcn_mfma_f32_16x16x32_f16(ah, bl, a, 0, 0, 0);
        a = __builtin_amdgcn_mfma_f32_16x16x32_f16(al, bh, a, 0, 0, 0);
        acc[mt][nt] = a;
      }
    }
  }
  float* O = covp + ((size_t)kc*4 + m) * 65536;
#pragma unroll
  for (int mt = 0; mt < 2; mt++)
#pragma unroll
    for (int nt = 0; nt < 4; nt++)
#pragma unroll
      for (int i = 0; i < 4; i++)
        O[(size_t)(v0 + wv*32 + mt*16 + quad*4 + i)*C_ + (u0 + wu*64 + nt*16 + lx16)] =
            acc[mt][nt][i];
}

// ---------------- trace from partials -> cnrm = (tr/256)*1.3 ----------------
__global__ __launch_bounds__(256) void k_trace2(const float* covp, const float* means,
                                                float* cnrm) {
  int m = blockIdx.x, t = threadIdx.x;
  float s = 0.f;
#pragma unroll
  for (int kc = 0; kc < KSPLIT; kc++)
    s += covp[((size_t)kc*4 + m)*65536 + (size_t)t*257];
  float mi = means[m*C_ + t];
  float d = (s - (float)N_*mi*mi) * (1.f/(float)(N_-1));
  __shared__ float red[256];
  red[t] = d; __syncthreads();
  for (int off = 128; off > 0; off >>= 1) { if (t < off) red[t] += red[t + off]; __syncthreads(); }
  if (!t) cnrm[m] = red[0] * (1.3f/256.f);
}

// ---------------- merged covred + nsinit ----------------
__global__ __launch_bounds__(256) void k_covred_init(const float* covp, const float* means,
                                                     const float* cnrm, float* Y, float* Z) {
  int i = blockIdx.x, m = blockIdx.y, j = threadIdx.x;
  float s = 0.f;
#pragma unroll
  for (int kc = 0; kc < KSPLIT; kc++)
    s += covp[((size_t)kc*4 + m)*65536 + (size_t)i*C_ + j];
  float mi = means[m*C_ + i], mj = means[m*C_ + j];
  float cv = (s - (float)N_*mi*mj) * (1.f/(float)(N_-1));
  size_t o = (size_t)m*65536 + (size_t)i*C_ + j;
  Y[o] = cv / cnrm[m];
  Z[o] = (i == j) ? 1.f : 0.f;
}

// ---------------- NS phase A: T = 3I - Z*Y ----------------
__global__ __launch_bounds__(256) void k_nsA(const float* Zin, const float* Yin, float* T) {
  int m = blockIdx.y;
  const float* A = Zin + (size_t)m*65536;
  const float* B = Yin + (size_t)m*65536;
  float* O = T + (size_t)m*65536;
  __shared__ float As[32][33], Bs[32][33];
  int t = threadIdx.x, tx = t & 15, ty = t >> 4;
  int m0 = (blockIdx.x >> 3) * 32, n0 = (blockIdx.x & 7) * 32;
  float acc[2][2] = {};
  for (int k0 = 0; k0 < 256; k0 += 32) {
#pragma unroll
    for (int l = 0; l < 4; l++) {
      int e = t + l * 256;
      int rr = e >> 5, cc = e & 31;
      As[rr][cc] = A[(size_t)(m0+rr)*256 + k0+cc];
      Bs[rr][cc] = B[(size_t)(k0+rr)*256 + n0+cc];
    }
    __syncthreads();
#pragma unroll
    for (int kk = 0; kk < 32; kk++) {
      float a0 = As[ty*2][kk], a1 = As[ty*2+1][kk];
      float b0 = Bs[kk][tx*2], b1 = Bs[kk][tx*2+1];
      acc[0][0] += a0*b0; acc[0][1] += a0*b1; acc[1][0] += a1*b0; acc[1][1] += a1*b1;
    }
    __syncthreads();
  }
#pragma unroll
  for (int a = 0; a < 2; a++)
#pragma unroll
    for (int b = 0; b < 2; b++) {
      int r = m0 + ty*2 + a, c = n0 + tx*2 + b;
      O[(size_t)r*256 + c] = (r == c) ? 3.f - acc[a][b] : -acc[a][b];
    }
}

// ---------------- NS phase B ----------------
__global__ __launch_bounds__(256) void k_nsB(const float* Yin, const float* Zin, const float* T,
                                             float* Yout, float* Zout) {
  int m = blockIdx.y, z = blockIdx.z;
  const float* A = (z == 0 ? Yin : T) + (size_t)m*65536;
  const float* B = (z == 0 ? T : Zin) + (size_t)m*65536;
  float* O = (z == 0 ? Yout : Zout) + (size_t)m*65536;
  __shared__ float As[32][33], Bs[32][33];
  int t = threadIdx.x, tx = t & 15, ty = t >> 4;
  int m0 = (blockIdx.x >> 3) * 32, n0 = (blockIdx.x & 7) * 32;
  float acc[2][2] = {};
  for (int k0 = 0; k0 < 256; k0 += 32) {
#pragma unroll
    for (int l = 0; l < 4; l++) {
      int e = t + l * 256;
      int rr = e >> 5, cc = e & 31;
      As[rr][cc] = A[(size_t)(m0+rr)*256 + k0+cc];
      Bs[rr][cc] = B[(size_t)(k0+rr)*256 + n0+cc];
    }
    __syncthreads();
#pragma unroll
    for (int kk = 0; kk < 32; kk++) {
      float a0 = As[ty*2][kk], a1 = As[ty*2+1][kk];
      float b0 = Bs[kk][tx*2], b1 = Bs[kk][tx*2+1];
      acc[0][0] += a0*b0; acc[0][1] += a0*b1; acc[1][0] += a1*b0; acc[1][1] += a1*b1;
    }
    __syncthreads();
  }
#pragma unroll
  for (int a = 0; a < 2; a++)
#pragma unroll
    for (int b = 0; b < 2; b++)
      O[(size_t)(m0+ty*2+a)*256 + n0+tx*2+b] = 0.5f * acc[a][b];
}

// ---------------- whiten ----------------
__global__ __launch_bounds__(256) void k_whiten(const float* content, const float* style,
                                                const float* Zall, const float* means,
                                                const float* cnrm, float* nc, float* ns) {
  int m = blockIdx.z;
  const float* x = (m < 2 ? content : style) + (size_t)(m & 1) * CN;
  float* outp = (m < 2 ? nc : ns) + (size_t)(m & 1) * CN;
  const float* Zm = Zall + (size_t)m*65536;
  const float* mean = means + m*C_;
  __shared__ float As[16][68], Bs[16][64];
  int t = threadIdx.x, tx = t & 15, ty = t >> 4;
  int n0 = blockIdx.x * 64, m0 = blockIdx.y * 64;
  float acc[4][4] = {};
  for (int k0 = 0; k0 < 256; k0 += 16) {
#pragma unroll
    for (int l = 0; l < 4; l++) {
      int e = t + l*256;
      { int kk = e & 15, mm = e >> 4; As[kk][mm] = Zm[(size_t)(m0+mm)*256 + k0+kk]; }
      { int nn = e & 63, kk = e >> 6;
        Bs[kk][nn] = x[(size_t)(k0+kk)*N_ + n0+nn] - mean[k0+kk]; }
    }
    __syncthreads();
#pragma unroll
    for (int kk = 0; kk < 16; kk++) {
      float4 b = *(const float4*)&Bs[kk][tx*4];
      fma16(acc, As[kk][ty*4+0], As[kk][ty*4+1], As[kk][ty*4+2], As[kk][ty*4+3], b);
    }
    __syncthreads();
  }
  float scale = 1.0f / sqrtf(cnrm[m]);
#pragma unroll
  for (int i = 0; i < 4; i++) {
    float4 o = make_float4(acc[i][0]*scale, acc[i][1]*scale, acc[i][2]*scale, acc[i][3]*scale);
    *(float4*)&outp[(size_t)(m0+ty*4+i)*N_ + n0 + tx*4] = o;
  }
}

// ---------------- per-pixel channel sum-of-squares of ns ----------------
__global__ __launch_bounds__(256) void k_ssq(const float* ns, float* ssq) {
  int b = blockIdx.y; int p = blockIdx.x * 256 + threadIdx.x;
  float acc = 0.f;
  for (int c = 0; c < C_; c++) { float v = ns[(size_t)b*CN + (size_t)c*N_ + p]; acc += v*v; }
  ssq[b*N_ + p] = acc;
}

// ---------------- patch reciprocal norms ----------------
__global__ __launch_bounds__(256) void k_rnorm(const float* ssq, float* rnorm) {
  int b = blockIdx.y; int s = blockIdx.x * 256 + threadIdx.x;
  int sy = s >> 6, sx = s & 63;
  float sum = 0.f;
#pragma unroll
  for (int ky = 0; ky < 3; ky++)
#pragma unroll
    for (int kx = 0; kx < 3; kx++)
      sum += ssq[b*N_ + refl(sy+ky-1)*64 + refl(sx+kx-1)];
  rnorm[b*N_ + s] = 1.f / (sqrtf(sum) + EPSF);
}

// ---------------- transpose + 2-way fp16 split for ONE batch: [c][v] -> [v][c] h/l ----------------
__global__ __launch_bounds__(256) void k_split(const float* nc_b, const float* ns_b,
                                               unsigned short* ncTh, unsigned short* ncTl,
                                               unsigned short* nsTh, unsigned short* nsTl) {
  int w = blockIdx.z;
  const float* src = w ? ns_b : nc_b;
  unsigned short* dh = w ? nsTh : ncTh;
  unsigned short* dl = w ? nsTl : ncTl;
  int u0 = blockIdx.x * 32, c0 = blockIdx.y * 32;
  __shared__ float tile[32][33];
  int t = threadIdx.x;
#pragma unroll
  for (int l = 0; l < 4; l++) {
    int e = t + l*256; int cc = e >> 5, uu = e & 31;
    tile[cc][uu] = src[(size_t)(c0+cc)*N_ + u0+uu];
  }
  __syncthreads();
#pragma unroll
  for (int l = 0; l < 4; l++) {
    int e = t + l*256; int uu = e >> 5, cc = e & 31;
    float v = tile[cc][uu];
    unsigned short h = f2h(v);
    float r1 = v - h2f(h);
    unsigned short lo = f2h(r1);
    size_t o = (size_t)(u0+uu)*C_ + c0+cc;
    dh[o] = h; dl[o] = lo;
  }
}

// ---------------- Gram via 2-way-split fp16 MFMA + fused x-blur ----------------
// K-stage = 64, GSTR = 72 ushorts (144 B; bank-class step 9==1 mod 8): staged writes
// (row=t>>3, seg=t&7) and frag reads (class = row+4ks+q mod 8) are conflict-free per
// 8-lane group. Fragment loads hoisted: 12 b128 reads then 24 MFMAs per k=32 subtile
// (was 20 reads unhoisted). LDS 73728 B -> 2 blocks/CU; 4 stages (half the barriers).
__global__ __launch_bounds__(512) void k_gram(const unsigned short* Ah_g, const unsigned short* Al_g,
                                              const unsigned short* Bh_g, const unsigned short* Bl_g,
                                              float* Hx) {
  __shared__ unsigned short sm[4*128*GSTR];  // 73728 B; epilogue Gs[64][133] fp32 unioned
  const int P = 128*GSTR;
  int t = threadIdx.x;
  int v0 = blockIdx.y * 128, u0 = blockIdx.x * 128;
  int wave = t >> 6, lane = t & 63;
  int wv = wave >> 1, wu = wave & 1;
  int lx16 = lane & 15, quad = lane >> 4;
  int srow = t >> 3, sseg = (t & 7) * 8;     // 64 rows x 8 segs of 16 B; 2 halves for 128 rows
  f32x4 acc[2][4];
#pragma unroll
  for (int i = 0; i < 2; i++)
#pragma unroll
    for (int j = 0; j < 4; j++) acc[i][j] = (f32x4){0.f, 0.f, 0.f, 0.f};

  for (int k0 = 0; k0 < 256; k0 += 64) {
    __syncthreads();
#pragma unroll
    for (int half = 0; half < 2; half++) {
      int r = srow + half*64;
      size_t goA = (size_t)(v0 + r)*C_ + k0 + sseg;
      size_t goB = (size_t)(u0 + r)*C_ + k0 + sseg;
      int lo_ = r*GSTR + sseg;
      *(float4*)&sm[0*P + lo_] = *(const float4*)&Ah_g[goA];
      *(float4*)&sm[1*P + lo_] = *(const float4*)&Al_g[goA];
      *(float4*)&sm[2*P + lo_] = *(const float4*)&Bh_g[goB];
      *(float4*)&sm[3*P + lo_] = *(const float4*)&Bl_g[goB];
    }
    __syncthreads();
#pragma unroll
    for (int ks = 0; ks < 2; ks++) {
      int kb = ks*32 + quad*8;
      f16x8 ah[2], al[2];
#pragma unroll
      for (int mt = 0; mt < 2; mt++) {
        int arow = (wv*32 + mt*16 + lx16)*GSTR + kb;
        ah[mt] = *(const f16x8*)&sm[0*P + arow];
        al[mt] = *(const f16x8*)&sm[1*P + arow];
      }
      f16x8 bh[4], bl[4];
#pragma unroll
      for (int nt = 0; nt < 4; nt++) {
        int brow = (wu*64 + nt*16 + lx16)*GSTR + kb;
        bh[nt] = *(const f16x8*)&sm[2*P + brow];
        bl[nt] = *(const f16x8*)&sm[3*P + brow];
      }
#pragma unroll
      for (int mt = 0; mt < 2; mt++)
#pragma unroll
        for (int nt = 0; nt < 4; nt++) {
          f32x4 a = acc[mt][nt];
          a = __builtin_amdgcn_mfma_f32_16x16x32_f16(ah[mt], bh[nt], a, 0, 0, 0);
          a = __builtin_amdgcn_mfma_f32_16x16x32_f16(ah[mt], bl[nt], a, 0, 0, 0);
          a = __builtin_amdgcn_mfma_f32_16x16x32_f16(al[mt], bh[nt], a, 0, 0, 0);
          acc[mt][nt] = a;
        }
    }
  }
  // epilogue: per 64-row half h, x-diagonal blur. Gs stride 133 fp32.
  float* Gs = (float*)sm;
  int btx = t & 15, bty = t >> 4;            // bty 0..31
#pragma unroll
  for (int h = 0; h < 2; h++) {
    __syncthreads();
    if ((wv >> 1) == h) {                    // waves with wv in {2h,2h+1} own rows h*64..+63
      int rbase = (wv & 1) * 32;
#pragma unroll
      for (int mt = 0; mt < 2; mt++)
#pragma unroll
        for (int nt = 0; nt < 4; nt++)
#pragma unroll
          for (int i = 0; i < 4; i++)
            Gs[(rbase + mt*16 + quad*4 + i)*133 + wu*64 + nt*16 + lx16] = acc[mt][nt][i];
    }
    __syncthreads();
#pragma unroll
    for (int i = 0; i < 2; i++) {
      int px = bty*2 + i;
      int xm = refl(px-1), xp = refl(px+1);
#pragma unroll
      for (int jh = 0; jh < 2; jh++) {
        int ub = jh*64;
        float tmp[4];
#pragma unroll
        for (int j = 0; j < 4; j++) {
          int sx = btx*4 + j;
          int smm = refl(sx-1), sp = refl(sx+1);
          tmp[j] = Gs[xm*133 + ub + smm] + Gs[px*133 + ub + sx] + Gs[xp*133 + ub + sp];
        }
        *(float4*)&Hx[(size_t)(v0 + h*64 + px)*N_ + u0 + ub + btx*4] =
            make_float4(tmp[0], tmp[1], tmp[2], tmp[3]);
      }
    }
  }
}

// ---------------- y-diagonal blur of Hx + argmax (rolling 3-row window) ----------------
// Block = (px, py-quarter). Keeps ring[3][4096] of Hx rows (v = yy*64+px) in LDS; each
// needed row loaded ONCE per block -> total reads ~1.15x Hx (was 3x with row-per-block).
// score(p=(py,px), s=(sy,sx)) = sum_d Hx[refl(py+d)*64+px][refl(sy+d)*64+sx] * rnorm[s].
__global__ __launch_bounds__(256) void k_argmax(const float* Hx, const float* rnorm,
                                                int* idx, int b) {
  int px = blockIdx.x, q = blockIdx.y, t = threadIdx.x;
  int py0 = q * 16;
  __shared__ float ring[3][4096];
  __shared__ float sv[256]; __shared__ int si[256];
  // preload rows refl(py0-1) and py0 (slot = row % 3; py-1,py,py+1 have distinct mod 3)
  int rA = refl(py0 - 1), rB = py0;
  {
    const float4* src = (const float4*)&Hx[(size_t)(rA*64 + px)*N_];
    float4* dst = (float4*)ring[rA % 3];
    for (int k = t; k < 1024; k += 256) dst[k] = src[k];
    src = (const float4*)&Hx[(size_t)(rB*64 + px)*N_];
    dst = (float4*)ring[rB % 3];
    for (int k = t; k < 1024; k += 256) dst[k] = src[k];
  }
  int maxloaded = (py0 == 0) ? 1 : py0;
  for (int py = py0; py < py0 + 16; py++) {
    int ym = refl(py - 1), yp = refl(py + 1);
    if (yp > maxloaded) {                    // block-uniform branch
      __syncthreads();                       // prior compute done before slot overwrite
      const float4* src = (const float4*)&Hx[(size_t)(yp*64 + px)*N_];
      float4* dst = (float4*)ring[yp % 3];
      for (int k = t; k < 1024; k += 256) dst[k] = src[k];
      maxloaded = yp;
    }
    __syncthreads();
    const float* Rm = ring[ym % 3];
    const float* R0 = ring[py % 3];
    const float* Rp = ring[yp % 3];
    float bv = -1e30f; int bs = 0;
#pragma unroll
    for (int k = 0; k < 16; k++) {
      int s = t + k*256;
      int sy = s >> 6, sx = s & 63;
      int um = refl(sy-1)*64 + sx, up = refl(sy+1)*64 + sx;
      float sc = (Rm[um] + R0[s] + Rp[up]) * rnorm[b*N_ + s];
      if (sc > bv) { bv = sc; bs = s; }
    }
    sv[t] = bv; si[t] = bs; __syncthreads();
    for (int off = 128; off > 0; off >>= 1) {
      if (t < off) {
        if (sv[t+off] > sv[t] || (sv[t+off] == sv[t] && si[t+off] < si[t])) {
          sv[t] = sv[t+off]; si[t] = si[t+off];
        }
      }
      __syncthreads();
    }
    if (!t) idx[b*N_ + (py*64 + px)] = si[0];
  }
}

// ---------------- deconv gather for batch b: recont_b[p][c] from fp16 pair ----------------
__global__ __launch_bounds__(256) void k_recon(const unsigned short* nsTh,
                                               const unsigned short* nsTl,
                                               const int* idx_b, float* recont_b) {
  int p = blockIdx.x, c = threadIdx.x;
  int py = p >> 6, px = p & 63;
  float acc = 0.f;
#pragma unroll
  for (int dy = 0; dy < 3; dy++)
#pragma unroll
    for (int dx = 0; dx < 3; dx++) {
      int q = refl(py+dy-1)*64 + refl(px+dx-1);
      int s = idx_b[q];
      int sy = s >> 6, sx = s & 63;
      size_t o = (size_t)(refl(sy+1-dy)*64 + refl(sx+1-dx))*C_ + c;
      acc += h2f(nsTh[o]) + h2f(nsTl[o]);
    }
  float dc = ((py==0||py==63)?2.f:3.f) * ((px==0||px==63)?2.f:3.f);
  recont_b[(size_t)p*C_ + c] = acc / dc;
}

// ---------------- coloring (both batches via grid.z) ----------------
__global__ __launch_bounds__(256) void k_color(const float* Yall, const float* recont_all,
                                               const float* cnrm, const float* means,
                                               float* out_all) {
  int b = blockIdx.z;
  const float* Ym = Yall + (size_t)(2+b)*65536;
  const float* recont = recont_all + (size_t)b*CN;
  const float* smean = means + (2+b)*C_;
  float* out = out_all + (size_t)b*CN;
  __shared__ float As[16][68], Bs[16][68];
  int t = threadIdx.x, tx = t & 15, ty = t >> 4;
  int n0 = blockIdx.x * 64, m0 = blockIdx.y * 64;
  float acc[4][4] = {};
  for (int k0 = 0; k0 < 256; k0 += 16) {
#pragma unroll
    for (int l = 0; l < 4; l++) {
      int e = t + l*256;
      int kk = e & 15, q = e >> 4;
      As[kk][q] = Ym[(size_t)(m0+q)*256 + k0+kk];
      Bs[kk][q] = recont[(size_t)(n0+q)*256 + k0+kk];
    }
    __syncthreads();
#pragma unroll
    for (int kk = 0; kk < 16; kk++) {
      float4 b4 = make_float4(Bs[kk][tx*4+0], Bs[kk][tx*4+1], Bs[kk][tx*4+2], Bs[kk][tx*4+3]);
      fma16(acc, As[kk][ty*4+0], As[kk][ty*4+1], As[kk][ty*4+2], As[kk][ty*4+3], b4);
    }
    __syncthreads();
  }
  float scale = sqrtf(cnrm[2+b]);
#pragma unroll
  for (int i = 0; i < 4; i++) {
    int r = m0 + ty*4 + i;
    float sm = smean[r];
    float4 o = make_float4(acc[i][0]*scale + sm, acc[i][1]*scale + sm,
                           acc[i][2]*scale + sm, acc[i][3]*scale + sm);
    *(float4*)&out[(size_t)r*N_ + n0 + tx*4] = o;
  }
}

extern "C" void kernel_launch(void* const* d_in, const int* in_sizes, int n_in,
                              void* d_out, int out_size, void* d_ws, size_t ws_size,
                              hipStream_t stream) {
  const float* content = (const float*)d_in[0];
  const float* style   = (const float*)d_in[1];
  float* out = (float*)d_out;

  // workspace layout (floats); total ~102 MiB
  float* F = (float*)d_ws;
  float* means  = F + 0;         // 4*256
  float* cnrm   = F + 1024;      // 4
  float* Y      = F + 264192;    // NS buffers
  float* Z      = F + 526336;
  float* Y2     = F + 788480;
  float* Z2     = F + 1050624;
  float* T      = F + 1312768;
  float* nc     = F + 1574912;   // 2*CN fp32 (dead after split(1))
  float* ns     = F + 3672064;   // 2*CN fp32 (dead after split(1))
  float* nstslot= F + 5769216;   // 2*CN floats = 4 fp16 plane slots
  float* recont = F + 7866368;   // 2*CN fp32
  float* ssq    = F + 9963520;   // 2*4096
  float* rnorm  = F + 9971712;   // 2*4096
  int*   idx    = (int*)(F + 9979904); // 2*4096
  float* Hx     = F + 9988096;   // 4096*4096

  // cov-phase aliases inside Hx (dead until k_gram at step 8)
  unsigned short* covsp = (unsigned short*)Hx;
  float* covp = Hx + 2*(size_t)CN*2;   // = Hx + 4194304 floats

  unsigned short* nsTh = (unsigned short*)nstslot;
  unsigned short* nsTl = (unsigned short*)nstslot + (size_t)CN;
  unsigned short* ncTh = (unsigned short*)nstslot + 2*(size_t)CN;
  unsigned short* ncTl = (unsigned short*)nstslot + 3*(size_t)CN;

  // 1-4. means, fp16-split, MFMA cov partials, trace, covred+nsinit
  k_mean<<<dim3(256,4), 256, 0, stream>>>(content, style, means);
  k_splitcov<<<dim3(1024,4), 256, 0, stream>>>(content, style, covsp);
  k_covmm<<<dim3(KSPLIT,4,4), 512, 0, stream>>>(covsp, covp);
  k_trace2<<<4, 256, 0, stream>>>(covp, means, cnrm);
  k_covred_init<<<dim3(256,4), 256, 0, stream>>>(covp, means, cnrm, Y, Z);
  // 5. NS iterations
  float *Ya = Y, *Za = Z, *Yb = Y2, *Zb = Z2;
  for (int it = 0; it < NS_ITERS; it++) {
    k_nsA<<<dim3(64,4), 256, 0, stream>>>(Za, Ya, T);
    k_nsB<<<dim3(64,4,2), 256, 0, stream>>>(Ya, Za, T, Yb, Zb);
    float* tmp;
    tmp = Ya; Ya = Yb; Yb = tmp;
    tmp = Za; Za = Zb; Zb = tmp;
  }
  // 6. whitening
  k_whiten<<<dim3(64,4,4), 256, 0, stream>>>(content, style, Za, means, cnrm, nc, ns);
  // 7. patch norms
  k_ssq<<<dim3(16,2), 256, 0, stream>>>(ns, ssq);
  k_rnorm<<<dim3(16,2), 256, 0, stream>>>(ssq, rnorm);
  // 8. per batch: split -> MFMA gram + x-blur -> rolling y-blur+argmax -> recon
  for (int b = 0; b < 2; b++) {
    k_split<<<dim3(128,8,2), 256, 0, stream>>>(nc + (size_t)b*CN, ns + (size_t)b*CN,
                                               ncTh, ncTl, nsTh, nsTl);
    k_gram<<<dim3(32,32), 512, 0, stream>>>(ncTh, ncTl, nsTh, nsTl, Hx);
    k_argmax<<<dim3(64,4), 256, 0, stream>>>(Hx, rnorm, idx, b);
    k_recon<<<4096, 256, 0, stream>>>(nsTh, nsTl, idx + (size_t)b*N_,
                                      recont + (size_t)b*CN);
  }
  // 9. coloring
  k_color<<<dim3(64,4,2), 256, 0, stream>>>(Ya, recont, cnrm, means, out);
}

// Round 4
// 463.137 us; speedup vs baseline: 1.1083x; 1.1083x over previous
//
#include <hip/hip_runtime.h>
#include <hip/hip_bf16.h>

#define C_ 256
#define N_ 4096
#define CN (C_*N_)
#define EPSF 1e-5f
#define NS_ITERS 6
#define KSPLIT 16  // split-K for MFMA cov partials
#define LSTR 40   // LDS row stride in ushort for covmm (80 B)
#define GSTR 72   // gram LDS row stride in ushort: 144 B -> bank-class step 9==1 mod 8
                  // => consecutive-8-lane groups conflict-free on staged writes AND frag reads

typedef _Float16 f16x8 __attribute__((ext_vector_type(8)));
typedef float f32x4 __attribute__((ext_vector_type(4)));

__device__ __forceinline__ int refl(int t) {
  return t < 0 ? -t : (t > 63 ? 126 - t : t);
}

// fp16 2-way split: v = h + l exact to ~2^-22 rel. Products hh+hl+lh drop only ll
// ~2^-22 rel — below the fp32 reference's own accumulation noise.
__device__ __forceinline__ unsigned short f2h(float x) {
  _Float16 h = (_Float16)x;
  return __builtin_bit_cast(unsigned short, h);
}
__device__ __forceinline__ float h2f(unsigned short u) {
  return (float)__builtin_bit_cast(_Float16, u);
}

__device__ __forceinline__ void fma16(float acc[4][4], float a0, float a1, float a2, float a3, float4 b) {
  acc[0][0] += a0*b.x; acc[0][1] += a0*b.y; acc[0][2] += a0*b.z; acc[0][3] += a0*b.w;
  acc[1][0] += a1*b.x; acc[1][1] += a1*b.y; acc[1][2] += a1*b.z; acc[1][3] += a1*b.w;
  acc[2][0] += a2*b.x; acc[2][1] += a2*b.y; acc[2][2] += a2*b.z; acc[2][3] += a2*b.w;
  acc[3][0] += a3*b.x; acc[3][1] += a3*b.y; acc[3][2] += a3*b.z; acc[3][3] += a3*b.w;
}

// ---------------- means ----------------
__global__ __launch_bounds__(256) void k_mean(const float* content, const float* style,
                                              float* means) {
  int c = blockIdx.x, m = blockIdx.y, t = threadIdx.x;
  const float* x = (m < 2 ? content : style) + (size_t)(m & 1) * CN + (size_t)c * N_;
  float s = 0.f;
  for (int i = t; i < N_; i += 256) s += x[i];
  __shared__ float red[256];
  red[t] = s; __syncthreads();
  for (int off = 128; off > 0; off >>= 1) { if (t < off) red[t] += red[t + off]; __syncthreads(); }
  if (t == 0) means[m * C_ + c] = red[0] * (1.f / N_);
}

// ---------------- 2-way fp16 split of raw content/style for MFMA cov ----------------
__global__ __launch_bounds__(256) void k_splitcov(const float* content, const float* style,
                                                  unsigned short* sp) {
  int m = blockIdx.y;
  const float* x = (m < 2 ? content : style) + (size_t)(m & 1) * CN;
  size_t base = (size_t)m * 2 * (size_t)CN;
  size_t i = ((size_t)blockIdx.x * 256 + threadIdx.x) * 4;
  float4 v = *(const float4*)&x[i];
  float vv[4] = {v.x, v.y, v.z, v.w};
  unsigned short h[4], lo[4];
#pragma unroll
  for (int j = 0; j < 4; j++) {
    unsigned short hh = f2h(vv[j]);
    float r1 = vv[j] - h2f(hh);
    h[j] = hh; lo[j] = f2h(r1);
  }
  *(ushort4*)&sp[base + i]      = make_ushort4(h[0], h[1], h[2], h[3]);
  *(ushort4*)&sp[base + CN + i] = make_ushort4(lo[0], lo[1], lo[2], lo[3]);
}

// ---------------- covariance raw sums via 3-term fp16 MFMA, split-K ----------------
__global__ __launch_bounds__(512) void k_covmm(const unsigned short* sp, float* covp) {
  __shared__ unsigned short sm[4*128*LSTR];   // 40960 B
  const int P = 128*LSTR;
  int t = threadIdx.x;
  int kc = blockIdx.x, m = blockIdx.z;
  int ti = blockIdx.y >> 1, tj = blockIdx.y & 1;
  const unsigned short* Xh = sp + (size_t)m * 2 * (size_t)CN;
  const unsigned short* Xl = Xh + CN;
  int v0 = ti * 128, u0 = tj * 128;
  int wave = t >> 6, lane = t & 63;
  int wv = wave >> 1, wu = wave & 1;
  int lx16 = lane & 15, quad = lane >> 4;
  int srow = t >> 2, sseg = (t & 3) * 8;
  f32x4 acc[2][4];
#pragma unroll
  for (int i = 0; i < 2; i++)
#pragma unroll
    for (int j = 0; j < 4; j++) acc[i][j] = (f32x4){0.f, 0.f, 0.f, 0.f};

  int kbeg = kc * (N_ / KSPLIT), kend = kbeg + (N_ / KSPLIT);
  for (int k0 = kbeg; k0 < kend; k0 += 32) {
    __syncthreads();
    {
      size_t goA = (size_t)(v0 + srow) * N_ + k0 + sseg;
      size_t goB = (size_t)(u0 + srow) * N_ + k0 + sseg;
      int lo_ = srow * LSTR + sseg;
      *(float4*)&sm[0*P + lo_] = *(const float4*)&Xh[goA];
      *(float4*)&sm[1*P + lo_] = *(const float4*)&Xl[goA];
      *(float4*)&sm[2*P + lo_] = *(const float4*)&Xh[goB];
      *(float4*)&sm[3*P + lo_] = *(const float4*)&Xl[goB];
    }
    __syncthreads();
#pragma unroll
    for (int mt = 0; mt < 2; mt++) {
      int arow = (wv*32 + mt*16 + lx16)*LSTR + quad*8;
      f16x8 ah = *(const f16x8*)&sm[0*P + arow];
      f16x8 al = *(const f16x8*)&sm[1*P + arow];
#pragma unroll
      for (int nt = 0; nt < 4; nt++) {
        int brow = (wu*64 + nt*16 + lx16)*LSTR + quad*8;
        f16x8 bh = *(const f16x8*)&sm[2*P + brow];
        f16x8 bl = *(const f16x8*)&sm[3*P + brow];
        f32x4 a = acc[mt][nt];
        a = __builtin_amdgcn_mfma_f32_16x16x32_f16(ah, bh, a, 0, 0, 0);
        a = __builtin_amdgcn_mfma_f32_16x16x32_f16(ah, bl, a, 0, 0, 0);
        a = __builtin_amdgcn_mfma_f32_16x16x32_f16(al, bh, a, 0, 0, 0);
        acc[mt][nt] = a;
      }
    }
  }
  float* O = covp + ((size_t)kc*4 + m) * 65536;
#pragma unroll
  for (int mt = 0; mt < 2; mt++)
#pragma unroll
    for (int nt = 0; nt < 4; nt++)
#pragma unroll
      for (int i = 0; i < 4; i++)
        O[(size_t)(v0 + wv*32 + mt*16 + quad*4 + i)*C_ + (u0 + wu*64 + nt*16 + lx16)] =
            acc[mt][nt][i];
}

// ---------------- trace from partials -> cnrm = (tr/256)*1.3 ----------------
__global__ __launch_bounds__(256) void k_trace2(const float* covp, const float* means,
                                                float* cnrm) {
  int m = blockIdx.x, t = threadIdx.x;
  float s = 0.f;
#pragma unroll
  for (int kc = 0; kc < KSPLIT; kc++)
    s += covp[((size_t)kc*4 + m)*65536 + (size_t)t*257];
  float mi = means[m*C_ + t];
  float d = (s - (float)N_*mi*mi) * (1.f/(float)(N_-1));
  __shared__ float red[256];
  red[t] = d; __syncthreads();
  for (int off = 128; off > 0; off >>= 1) { if (t < off) red[t] += red[t + off]; __syncthreads(); }
  if (!t) cnrm[m] = red[0] * (1.3f/256.f);
}

// ---------------- merged covred + nsinit ----------------
__global__ __launch_bounds__(256) void k_covred_init(const float* covp, const float* means,
                                                     const float* cnrm, float* Y, float* Z) {
  int i = blockIdx.x, m = blockIdx.y, j = threadIdx.x;
  float s = 0.f;
#pragma unroll
  for (int kc = 0; kc < KSPLIT; kc++)
    s += covp[((size_t)kc*4 + m)*65536 + (size_t)i*C_ + j];
  float mi = means[m*C_ + i], mj = means[m*C_ + j];
  float cv = (s - (float)N_*mi*mj) * (1.f/(float)(N_-1));
  size_t o = (size_t)m*65536 + (size_t)i*C_ + j;
  Y[o] = cv / cnrm[m];
  Z[o] = (i == j) ? 1.f : 0.f;
}

// ---------------- NS phase A: T = 3I - Z*Y ----------------
__global__ __launch_bounds__(256) void k_nsA(const float* Zin, const float* Yin, float* T) {
  int m = blockIdx.y;
  const float* A = Zin + (size_t)m*65536;
  const float* B = Yin + (size_t)m*65536;
  float* O = T + (size_t)m*65536;
  __shared__ float As[32][33], Bs[32][33];
  int t = threadIdx.x, tx = t & 15, ty = t >> 4;
  int m0 = (blockIdx.x >> 3) * 32, n0 = (blockIdx.x & 7) * 32;
  float acc[2][2] = {};
  for (int k0 = 0; k0 < 256; k0 += 32) {
#pragma unroll
    for (int l = 0; l < 4; l++) {
      int e = t + l * 256;
      int rr = e >> 5, cc = e & 31;
      As[rr][cc] = A[(size_t)(m0+rr)*256 + k0+cc];
      Bs[rr][cc] = B[(size_t)(k0+rr)*256 + n0+cc];
    }
    __syncthreads();
#pragma unroll
    for (int kk = 0; kk < 32; kk++) {
      float a0 = As[ty*2][kk], a1 = As[ty*2+1][kk];
      float b0 = Bs[kk][tx*2], b1 = Bs[kk][tx*2+1];
      acc[0][0] += a0*b0; acc[0][1] += a0*b1; acc[1][0] += a1*b0; acc[1][1] += a1*b1;
    }
    __syncthreads();
  }
#pragma unroll
  for (int a = 0; a < 2; a++)
#pragma unroll
    for (int b = 0; b < 2; b++) {
      int r = m0 + ty*2 + a, c = n0 + tx*2 + b;
      O[(size_t)r*256 + c] = (r == c) ? 3.f - acc[a][b] : -acc[a][b];
    }
}

// ---------------- NS phase B ----------------
__global__ __launch_bounds__(256) void k_nsB(const float* Yin, const float* Zin, const float* T,
                                             float* Yout, float* Zout) {
  int m = blockIdx.y, z = blockIdx.z;
  const float* A = (z == 0 ? Yin : T) + (size_t)m*65536;
  const float* B = (z == 0 ? T : Zin) + (size_t)m*65536;
  float* O = (z == 0 ? Yout : Zout) + (size_t)m*65536;
  __shared__ float As[32][33], Bs[32][33];
  int t = threadIdx.x, tx = t & 15, ty = t >> 4;
  int m0 = (blockIdx.x >> 3) * 32, n0 = (blockIdx.x & 7) * 32;
  float acc[2][2] = {};
  for (int k0 = 0; k0 < 256; k0 += 32) {
#pragma unroll
    for (int l = 0; l < 4; l++) {
      int e = t + l * 256;
      int rr = e >> 5, cc = e & 31;
      As[rr][cc] = A[(size_t)(m0+rr)*256 + k0+cc];
      Bs[rr][cc] = B[(size_t)(k0+rr)*256 + n0+cc];
    }
    __syncthreads();
#pragma unroll
    for (int kk = 0; kk < 32; kk++) {
      float a0 = As[ty*2][kk], a1 = As[ty*2+1][kk];
      float b0 = Bs[kk][tx*2], b1 = Bs[kk][tx*2+1];
      acc[0][0] += a0*b0; acc[0][1] += a0*b1; acc[1][0] += a1*b0; acc[1][1] += a1*b1;
    }
    __syncthreads();
  }
#pragma unroll
  for (int a = 0; a < 2; a++)
#pragma unroll
    for (int b = 0; b < 2; b++)
      O[(size_t)(m0+ty*2+a)*256 + n0+tx*2+b] = 0.5f * acc[a][b];
}

// ---------------- whiten ----------------
__global__ __launch_bounds__(256) void k_whiten(const float* content, const float* style,
                                                const float* Zall, const float* means,
                                                const float* cnrm, float* nc, float* ns) {
  int m = blockIdx.z;
  const float* x = (m < 2 ? content : style) + (size_t)(m & 1) * CN;
  float* outp = (m < 2 ? nc : ns) + (size_t)(m & 1) * CN;
  const float* Zm = Zall + (size_t)m*65536;
  const float* mean = means + m*C_;
  __shared__ float As[16][68], Bs[16][64];
  int t = threadIdx.x, tx = t & 15, ty = t >> 4;
  int n0 = blockIdx.x * 64, m0 = blockIdx.y * 64;
  float acc[4][4] = {};
  for (int k0 = 0; k0 < 256; k0 += 16) {
#pragma unroll
    for (int l = 0; l < 4; l++) {
      int e = t + l*256;
      { int kk = e & 15, mm = e >> 4; As[kk][mm] = Zm[(size_t)(m0+mm)*256 + k0+kk]; }
      { int nn = e & 63, kk = e >> 6;
        Bs[kk][nn] = x[(size_t)(k0+kk)*N_ + n0+nn] - mean[k0+kk]; }
    }
    __syncthreads();
#pragma unroll
    for (int kk = 0; kk < 16; kk++) {
      float4 b = *(const float4*)&Bs[kk][tx*4];
      fma16(acc, As[kk][ty*4+0], As[kk][ty*4+1], As[kk][ty*4+2], As[kk][ty*4+3], b);
    }
    __syncthreads();
  }
  float scale = 1.0f / sqrtf(cnrm[m]);
#pragma unroll
  for (int i = 0; i < 4; i++) {
    float4 o = make_float4(acc[i][0]*scale, acc[i][1]*scale, acc[i][2]*scale, acc[i][3]*scale);
    *(float4*)&outp[(size_t)(m0+ty*4+i)*N_ + n0 + tx*4] = o;
  }
}

// ---------------- per-pixel channel sum-of-squares of ns ----------------
__global__ __launch_bounds__(256) void k_ssq(const float* ns, float* ssq) {
  int b = blockIdx.y; int p = blockIdx.x * 256 + threadIdx.x;
  float acc = 0.f;
  for (int c = 0; c < C_; c++) { float v = ns[(size_t)b*CN + (size_t)c*N_ + p]; acc += v*v; }
  ssq[b*N_ + p] = acc;
}

// ---------------- patch reciprocal norms ----------------
__global__ __launch_bounds__(256) void k_rnorm(const float* ssq, float* rnorm) {
  int b = blockIdx.y; int s = blockIdx.x * 256 + threadIdx.x;
  int sy = s >> 6, sx = s & 63;
  float sum = 0.f;
#pragma unroll
  for (int ky = 0; ky < 3; ky++)
#pragma unroll
    for (int kx = 0; kx < 3; kx++)
      sum += ssq[b*N_ + refl(sy+ky-1)*64 + refl(sx+kx-1)];
  rnorm[b*N_ + s] = 1.f / (sqrtf(sum) + EPSF);
}

// ---------------- transpose + 2-way fp16 split for ONE batch: [c][v] -> [v][c] h/l ----------------
__global__ __launch_bounds__(256) void k_split(const float* nc_b, const float* ns_b,
                                               unsigned short* ncTh, unsigned short* ncTl,
                                               unsigned short* nsTh, unsigned short* nsTl) {
  int w = blockIdx.z;
  const float* src = w ? ns_b : nc_b;
  unsigned short* dh = w ? nsTh : ncTh;
  unsigned short* dl = w ? nsTl : ncTl;
  int u0 = blockIdx.x * 32, c0 = blockIdx.y * 32;
  __shared__ float tile[32][33];
  int t = threadIdx.x;
#pragma unroll
  for (int l = 0; l < 4; l++) {
    int e = t + l*256; int cc = e >> 5, uu = e & 31;
    tile[cc][uu] = src[(size_t)(c0+cc)*N_ + u0+uu];
  }
  __syncthreads();
#pragma unroll
  for (int l = 0; l < 4; l++) {
    int e = t + l*256; int uu = e >> 5, cc = e & 31;
    float v = tile[cc][uu];
    unsigned short h = f2h(v);
    float r1 = v - h2f(h);
    unsigned short lo = f2h(r1);
    size_t o = (size_t)(u0+uu)*C_ + c0+cc;
    dh[o] = h; dl[o] = lo;
  }
}

// ---------------- Gram via 2-way-split fp16 MFMA + fused x-blur ----------------
// K-stage = 64, GSTR = 72 ushorts (144 B; bank-class step 9==1 mod 8): staged writes
// (row=t>>3, seg=t&7) and frag reads conflict-free per 8-lane group. Fragment loads
// hoisted: 12 b128 reads then 24 MFMAs per k=32 subtile. LDS 73728 B -> 2 blocks/CU.
__global__ __launch_bounds__(512) void k_gram(const unsigned short* Ah_g, const unsigned short* Al_g,
                                              const unsigned short* Bh_g, const unsigned short* Bl_g,
                                              float* Hx) {
  __shared__ unsigned short sm[4*128*GSTR];  // 73728 B; epilogue Gs[64][133] fp32 unioned
  const int P = 128*GSTR;
  int t = threadIdx.x;
  int v0 = blockIdx.y * 128, u0 = blockIdx.x * 128;
  int wave = t >> 6, lane = t & 63;
  int wv = wave >> 1, wu = wave & 1;
  int lx16 = lane & 15, quad = lane >> 4;
  int srow = t >> 3, sseg = (t & 7) * 8;     // 64 rows x 8 segs of 16 B; 2 halves for 128 rows
  f32x4 acc[2][4];
#pragma unroll
  for (int i = 0; i < 2; i++)
#pragma unroll
    for (int j = 0; j < 4; j++) acc[i][j] = (f32x4){0.f, 0.f, 0.f, 0.f};

  for (int k0 = 0; k0 < 256; k0 += 64) {
    __syncthreads();
#pragma unroll
    for (int half = 0; half < 2; half++) {
      int r = srow + half*64;
      size_t goA = (size_t)(v0 + r)*C_ + k0 + sseg;
      size_t goB = (size_t)(u0 + r)*C_ + k0 + sseg;
      int lo_ = r*GSTR + sseg;
      *(float4*)&sm[0*P + lo_] = *(const float4*)&Ah_g[goA];
      *(float4*)&sm[1*P + lo_] = *(const float4*)&Al_g[goA];
      *(float4*)&sm[2*P + lo_] = *(const float4*)&Bh_g[goB];
      *(float4*)&sm[3*P + lo_] = *(const float4*)&Bl_g[goB];
    }
    __syncthreads();
#pragma unroll
    for (int ks = 0; ks < 2; ks++) {
      int kb = ks*32 + quad*8;
      f16x8 ah[2], al[2];
#pragma unroll
      for (int mt = 0; mt < 2; mt++) {
        int arow = (wv*32 + mt*16 + lx16)*GSTR + kb;
        ah[mt] = *(const f16x8*)&sm[0*P + arow];
        al[mt] = *(const f16x8*)&sm[1*P + arow];
      }
      f16x8 bh[4], bl[4];
#pragma unroll
      for (int nt = 0; nt < 4; nt++) {
        int brow = (wu*64 + nt*16 + lx16)*GSTR + kb;
        bh[nt] = *(const f16x8*)&sm[2*P + brow];
        bl[nt] = *(const f16x8*)&sm[3*P + brow];
      }
#pragma unroll
      for (int mt = 0; mt < 2; mt++)
#pragma unroll
        for (int nt = 0; nt < 4; nt++) {
          f32x4 a = acc[mt][nt];
          a = __builtin_amdgcn_mfma_f32_16x16x32_f16(ah[mt], bh[nt], a, 0, 0, 0);
          a = __builtin_amdgcn_mfma_f32_16x16x32_f16(ah[mt], bl[nt], a, 0, 0, 0);
          a = __builtin_amdgcn_mfma_f32_16x16x32_f16(al[mt], bh[nt], a, 0, 0, 0);
          acc[mt][nt] = a;
        }
    }
  }
  // epilogue: per 64-row half h, x-diagonal blur. Gs stride 133 fp32.
  float* Gs = (float*)sm;
  int btx = t & 15, bty = t >> 4;            // bty 0..31
#pragma unroll
  for (int h = 0; h < 2; h++) {
    __syncthreads();
    if ((wv >> 1) == h) {                    // waves with wv in {2h,2h+1} own rows h*64..+63
      int rbase = (wv & 1) * 32;
#pragma unroll
      for (int mt = 0; mt < 2; mt++)
#pragma unroll
        for (int nt = 0; nt < 4; nt++)
#pragma unroll
          for (int i = 0; i < 4; i++)
            Gs[(rbase + mt*16 + quad*4 + i)*133 + wu*64 + nt*16 + lx16] = acc[mt][nt][i];
    }
    __syncthreads();
#pragma unroll
    for (int i = 0; i < 2; i++) {
      int px = bty*2 + i;
      int xm = refl(px-1), xp = refl(px+1);
#pragma unroll
      for (int jh = 0; jh < 2; jh++) {
        int ub = jh*64;
        float tmp[4];
#pragma unroll
        for (int j = 0; j < 4; j++) {
          int sx = btx*4 + j;
          int smm = refl(sx-1), sp = refl(sx+1);
          tmp[j] = Gs[xm*133 + ub + smm] + Gs[px*133 + ub + sx] + Gs[xp*133 + ub + sp];
        }
        *(float4*)&Hx[(size_t)(v0 + h*64 + px)*N_ + u0 + ub + btx*4] =
            make_float4(tmp[0], tmp[1], tmp[2], tmp[3]);
      }
    }
  }
}

// ---------------- y-diagonal blur of Hx + argmax ----------------
// Round-2 structure (4096 blocks, full parallelism) + XCD-contiguous py-adjacent remap:
// v = (d&7)*512 + d>>3 gives XCD x the 8 px-columns [x*8, x*8+8), walking py
// sequentially. Consecutive same-XCD dispatches share 2 of 3 Hx rows -> each 16KB row
// HBM-fetched ~once, re-served from that XCD's private L2 (rows of a px never leave
// the XCD: all 3 readers are same-XCD by construction).
__global__ __launch_bounds__(256) void k_argmax(const float* Hx, const float* rnorm,
                                                int* idx, int b) {
  int d = blockIdx.x, t = threadIdx.x;
  int v = (d & 7) * 512 + (d >> 3);   // bijective: 4096 = 8*512
  int px = v >> 6, py = v & 63;
  int p = py * 64 + px;
  size_t r0 = (size_t)(refl(py-1)*64 + px) * N_;
  size_t r1 = (size_t)p * N_;
  size_t r2 = (size_t)(refl(py+1)*64 + px) * N_;
  float bv = -1e30f; int bs = 0;
  for (int s = t; s < N_; s += 256) {
    int sy = s >> 6, sx = s & 63;
    int u0 = refl(sy-1)*64 + sx, u2 = refl(sy+1)*64 + sx;
    float acc = Hx[r0 + u0] + Hx[r1 + s] + Hx[r2 + u2];
    float sc = acc * rnorm[b*N_ + s];
    if (sc > bv) { bv = sc; bs = s; }
  }
  __shared__ float sv[256]; __shared__ int si[256];
  sv[t] = bv; si[t] = bs; __syncthreads();
  for (int off = 128; off > 0; off >>= 1) {
    if (t < off) {
      if (sv[t+off] > sv[t] || (sv[t+off] == sv[t] && si[t+off] < si[t])) {
        sv[t] = sv[t+off]; si[t] = si[t+off];
      }
    }
    __syncthreads();
  }
  if (!t) idx[b*N_ + p] = si[0];
}

// ---------------- deconv gather for batch b: recont_b[p][c] from fp16 pair ----------------
__global__ __launch_bounds__(256) void k_recon(const unsigned short* nsTh,
                                               const unsigned short* nsTl,
                                               const int* idx_b, float* recont_b) {
  int p = blockIdx.x, c = threadIdx.x;
  int py = p >> 6, px = p & 63;
  float acc = 0.f;
#pragma unroll
  for (int dy = 0; dy < 3; dy++)
#pragma unroll
    for (int dx = 0; dx < 3; dx++) {
      int q = refl(py+dy-1)*64 + refl(px+dx-1);
      int s = idx_b[q];
      int sy = s >> 6, sx = s & 63;
      size_t o = (size_t)(refl(sy+1-dy)*64 + refl(sx+1-dx))*C_ + c;
      acc += h2f(nsTh[o]) + h2f(nsTl[o]);
    }
  float dc = ((py==0||py==63)?2.f:3.f) * ((px==0||px==63)?2.f:3.f);
  recont_b[(size_t)p*C_ + c] = acc / dc;
}

// ---------------- coloring (both batches via grid.z) ----------------
__global__ __launch_bounds__(256) void k_color(const float* Yall, const float* recont_all,
                                               const float* cnrm, const float* means,
                                               float* out_all) {
  int b = blockIdx.z;
  const float* Ym = Yall + (size_t)(2+b)*65536;
  const float* recont = recont_all + (size_t)b*CN;
  const float* smean = means + (2+b)*C_;
  float* out = out_all + (size_t)b*CN;
  __shared__ float As[16][68], Bs[16][68];
  int t = threadIdx.x, tx = t & 15, ty = t >> 4;
  int n0 = blockIdx.x * 64, m0 = blockIdx.y * 64;
  float acc[4][4] = {};
  for (int k0 = 0; k0 < 256; k0 += 16) {
#pragma unroll
    for (int l = 0; l < 4; l++) {
      int e = t + l*256;
      int kk = e & 15, q = e >> 4;
      As[kk][q] = Ym[(size_t)(m0+q)*256 + k0+kk];
      Bs[kk][q] = recont[(size_t)(n0+q)*256 + k0+kk];
    }
    __syncthreads();
#pragma unroll
    for (int kk = 0; kk < 16; kk++) {
      float4 b4 = make_float4(Bs[kk][tx*4+0], Bs[kk][tx*4+1], Bs[kk][tx*4+2], Bs[kk][tx*4+3]);
      fma16(acc, As[kk][ty*4+0], As[kk][ty*4+1], As[kk][ty*4+2], As[kk][ty*4+3], b4);
    }
    __syncthreads();
  }
  float scale = sqrtf(cnrm[2+b]);
#pragma unroll
  for (int i = 0; i < 4; i++) {
    int r = m0 + ty*4 + i;
    float sm = smean[r];
    float4 o = make_float4(acc[i][0]*scale + sm, acc[i][1]*scale + sm,
                           acc[i][2]*scale + sm, acc[i][3]*scale + sm);
    *(float4*)&out[(size_t)r*N_ + n0 + tx*4] = o;
  }
}

extern "C" void kernel_launch(void* const* d_in, const int* in_sizes, int n_in,
                              void* d_out, int out_size, void* d_ws, size_t ws_size,
                              hipStream_t stream) {
  const float* content = (const float*)d_in[0];
  const float* style   = (const float*)d_in[1];
  float* out = (float*)d_out;

  // workspace layout (floats); total ~102 MiB
  float* F = (float*)d_ws;
  float* means  = F + 0;         // 4*256
  float* cnrm   = F + 1024;      // 4
  float* Y      = F + 264192;    // NS buffers
  float* Z      = F + 526336;
  float* Y2     = F + 788480;
  float* Z2     = F + 1050624;
  float* T      = F + 1312768;
  float* nc     = F + 1574912;   // 2*CN fp32 (dead after split(1))
  float* ns     = F + 3672064;   // 2*CN fp32 (dead after split(1))
  float* nstslot= F + 5769216;   // 2*CN floats = 4 fp16 plane slots
  float* recont = F + 7866368;   // 2*CN fp32
  float* ssq    = F + 9963520;   // 2*4096
  float* rnorm  = F + 9971712;   // 2*4096
  int*   idx    = (int*)(F + 9979904); // 2*4096
  float* Hx     = F + 9988096;   // 4096*4096

  // cov-phase aliases inside Hx (dead until k_gram at step 8)
  unsigned short* covsp = (unsigned short*)Hx;
  float* covp = Hx + 2*(size_t)CN*2;   // = Hx + 4194304 floats

  unsigned short* nsTh = (unsigned short*)nstslot;
  unsigned short* nsTl = (unsigned short*)nstslot + (size_t)CN;
  unsigned short* ncTh = (unsigned short*)nstslot + 2*(size_t)CN;
  unsigned short* ncTl = (unsigned short*)nstslot + 3*(size_t)CN;

  // 1-4. means, fp16-split, MFMA cov partials, trace, covred+nsinit
  k_mean<<<dim3(256,4), 256, 0, stream>>>(content, style, means);
  k_splitcov<<<dim3(1024,4), 256, 0, stream>>>(content, style, covsp);
  k_covmm<<<dim3(KSPLIT,4,4), 512, 0, stream>>>(covsp, covp);
  k_trace2<<<4, 256, 0, stream>>>(covp, means, cnrm);
  k_covred_init<<<dim3(256,4), 256, 0, stream>>>(covp, means, cnrm, Y, Z);
  // 5. NS iterations
  float *Ya = Y, *Za = Z, *Yb = Y2, *Zb = Z2;
  for (int it = 0; it < NS_ITERS; it++) {
    k_nsA<<<dim3(64,4), 256, 0, stream>>>(Za, Ya, T);
    k_nsB<<<dim3(64,4,2), 256, 0, stream>>>(Ya, Za, T, Yb, Zb);
    float* tmp;
    tmp = Ya; Ya = Yb; Yb = tmp;
    tmp = Za; Za = Zb; Zb = tmp;
  }
  // 6. whitening
  k_whiten<<<dim3(64,4,4), 256, 0, stream>>>(content, style, Za, means, cnrm, nc, ns);
  // 7. patch norms
  k_ssq<<<dim3(16,2), 256, 0, stream>>>(ns, ssq);
  k_rnorm<<<dim3(16,2), 256, 0, stream>>>(ssq, rnorm);
  // 8. per batch: split -> MFMA gram + x-blur -> y-blur+argmax -> recon
  for (int b = 0; b < 2; b++) {
    k_split<<<dim3(128,8,2), 256, 0, stream>>>(nc + (size_t)b*CN, ns + (size_t)b*CN,
                                               ncTh, ncTl, nsTh, nsTl);
    k_gram<<<dim3(32,32), 512, 0, stream>>>(ncTh, ncTl, nsTh, nsTl, Hx);
    k_argmax<<<4096, 256, 0, stream>>>(Hx, rnorm, idx, b);
    k_recon<<<4096, 256, 0, stream>>>(nsTh, nsTl, idx + (size_t)b*N_,
                                      recont + (size_t)b*CN);
  }
  // 9. coloring
  k_color<<<dim3(64,4,2), 256, 0, stream>>>(Ya, recont, cnrm, means, out);
}

// Round 5
// 404.022 us; speedup vs baseline: 1.2705x; 1.1463x over previous
//
#include <hip/hip_runtime.h>
#include <hip/hip_bf16.h>

#define C_ 256
#define N_ 4096
#define CN (C_*N_)
#define EPSF 1e-5f
#define NS_ITERS 6
#define KSPLIT 16  // split-K for MFMA cov partials
#define LSTR 40   // LDS row stride in ushort (80 B, 16B-aligned)

typedef _Float16 f16x8 __attribute__((ext_vector_type(8)));
typedef float f32x4 __attribute__((ext_vector_type(4)));

__device__ __forceinline__ int refl(int t) {
  return t < 0 ? -t : (t > 63 ? 126 - t : t);
}

// fp16 2-way split: v = h + l exact to ~2^-22 rel. Products hh+hl+lh drop only ll
// ~2^-22 rel — below the fp32 reference's own accumulation noise.
__device__ __forceinline__ unsigned short f2h(float x) {
  _Float16 h = (_Float16)x;
  return __builtin_bit_cast(unsigned short, h);
}
__device__ __forceinline__ float h2f(unsigned short u) {
  return (float)__builtin_bit_cast(_Float16, u);
}

__device__ __forceinline__ void fma16(float acc[4][4], float a0, float a1, float a2, float a3, float4 b) {
  acc[0][0] += a0*b.x; acc[0][1] += a0*b.y; acc[0][2] += a0*b.z; acc[0][3] += a0*b.w;
  acc[1][0] += a1*b.x; acc[1][1] += a1*b.y; acc[1][2] += a1*b.z; acc[1][3] += a1*b.w;
  acc[2][0] += a2*b.x; acc[2][1] += a2*b.y; acc[2][2] += a2*b.z; acc[2][3] += a2*b.w;
  acc[3][0] += a3*b.x; acc[3][1] += a3*b.y; acc[3][2] += a3*b.z; acc[3][3] += a3*b.w;
}

// ---------------- shared MFMA helper: 64x64 out tile of A·B^T, K=256, fp32 in ----------------
// On-the-fly fp16 h/l split during staging; 3-term MFMA (hh+hl+lh). 256 thr = 4 waves,
// wave (wv,wu) owns rows wv*32..+32, cols wu*32..+32 as 2x2 16x16 tiles.
// Valid for NS (all iterates symmetric+commuting -> A·B == A·B^T up to rounding) and for
// color (recont already [n][k] row-major). Both operands have leading dim 256.
__device__ __forceinline__ void mm64_3term(unsigned short* sm, const float* A, const float* B,
                                           int m0, int n0, f32x4 acc[2][2]) {
  const int P = 64*LSTR;
  int t = threadIdx.x;
  int lane = t & 63;
  int wv = (t >> 7) & 1, wu = (t >> 6) & 1;
  int lx16 = lane & 15, quad = lane >> 4;
  int srow = t >> 2, sseg = (t & 3) * 8;    // 256 thr = 64 rows x 4 segs of 8 floats
#pragma unroll
  for (int i = 0; i < 2; i++)
#pragma unroll
    for (int j = 0; j < 2; j++) acc[i][j] = (f32x4){0.f, 0.f, 0.f, 0.f};
  for (int k0 = 0; k0 < 256; k0 += 32) {
    __syncthreads();
    {
      const float* pa = &A[(size_t)(m0 + srow)*256 + k0 + sseg];
      const float* pb = &B[(size_t)(n0 + srow)*256 + k0 + sseg];
#pragma unroll
      for (int g = 0; g < 2; g++) {
        float4 va = *(const float4*)(pa + g*4);
        float4 vb = *(const float4*)(pb + g*4);
        float fa[4] = {va.x, va.y, va.z, va.w};
        float fb[4] = {vb.x, vb.y, vb.z, vb.w};
        unsigned short ha[4], la[4], hb[4], lb[4];
#pragma unroll
        for (int j = 0; j < 4; j++) {
          unsigned short h = f2h(fa[j]); ha[j] = h; la[j] = f2h(fa[j] - h2f(h));
          h = f2h(fb[j]); hb[j] = h; lb[j] = f2h(fb[j] - h2f(h));
        }
        int lo_ = srow*LSTR + sseg + g*4;
        *(ushort4*)&sm[0*P + lo_] = make_ushort4(ha[0], ha[1], ha[2], ha[3]);
        *(ushort4*)&sm[1*P + lo_] = make_ushort4(la[0], la[1], la[2], la[3]);
        *(ushort4*)&sm[2*P + lo_] = make_ushort4(hb[0], hb[1], hb[2], hb[3]);
        *(ushort4*)&sm[3*P + lo_] = make_ushort4(lb[0], lb[1], lb[2], lb[3]);
      }
    }
    __syncthreads();
    f16x8 ah[2], al[2], bh[2], bl[2];
#pragma unroll
    for (int mt = 0; mt < 2; mt++) {
      int arow = (wv*32 + mt*16 + lx16)*LSTR + quad*8;
      ah[mt] = *(const f16x8*)&sm[0*P + arow];
      al[mt] = *(const f16x8*)&sm[1*P + arow];
    }
#pragma unroll
    for (int nt = 0; nt < 2; nt++) {
      int brow = (wu*32 + nt*16 + lx16)*LSTR + quad*8;
      bh[nt] = *(const f16x8*)&sm[2*P + brow];
      bl[nt] = *(const f16x8*)&sm[3*P + brow];
    }
#pragma unroll
    for (int mt = 0; mt < 2; mt++)
#pragma unroll
      for (int nt = 0; nt < 2; nt++) {
        f32x4 a = acc[mt][nt];
        a = __builtin_amdgcn_mfma_f32_16x16x32_f16(ah[mt], bh[nt], a, 0, 0, 0);
        a = __builtin_amdgcn_mfma_f32_16x16x32_f16(ah[mt], bl[nt], a, 0, 0, 0);
        a = __builtin_amdgcn_mfma_f32_16x16x32_f16(al[mt], bh[nt], a, 0, 0, 0);
        acc[mt][nt] = a;
      }
  }
}

// ---------------- means ----------------
__global__ __launch_bounds__(256) void k_mean(const float* content, const float* style,
                                              float* means) {
  int c = blockIdx.x, m = blockIdx.y, t = threadIdx.x;
  const float* x = (m < 2 ? content : style) + (size_t)(m & 1) * CN + (size_t)c * N_;
  float s = 0.f;
  for (int i = t; i < N_; i += 256) s += x[i];
  __shared__ float red[256];
  red[t] = s; __syncthreads();
  for (int off = 128; off > 0; off >>= 1) { if (t < off) red[t] += red[t + off]; __syncthreads(); }
  if (t == 0) means[m * C_ + c] = red[0] * (1.f / N_);
}

// ---------------- 2-way fp16 split of raw content/style for MFMA cov ----------------
__global__ __launch_bounds__(256) void k_splitcov(const float* content, const float* style,
                                                  unsigned short* sp) {
  int m = blockIdx.y;
  const float* x = (m < 2 ? content : style) + (size_t)(m & 1) * CN;
  size_t base = (size_t)m * 2 * (size_t)CN;
  size_t i = ((size_t)blockIdx.x * 256 + threadIdx.x) * 4;
  float4 v = *(const float4*)&x[i];
  float vv[4] = {v.x, v.y, v.z, v.w};
  unsigned short h[4], lo[4];
#pragma unroll
  for (int j = 0; j < 4; j++) {
    unsigned short hh = f2h(vv[j]);
    float r1 = vv[j] - h2f(hh);
    h[j] = hh; lo[j] = f2h(r1);
  }
  *(ushort4*)&sp[base + i]      = make_ushort4(h[0], h[1], h[2], h[3]);
  *(ushort4*)&sp[base + CN + i] = make_ushort4(lo[0], lo[1], lo[2], lo[3]);
}

// ---------------- covariance raw sums via 3-term fp16 MFMA, split-K ----------------
__global__ __launch_bounds__(512) void k_covmm(const unsigned short* sp, float* covp) {
  __shared__ unsigned short sm[4*128*LSTR];   // 40960 B
  const int P = 128*LSTR;
  int t = threadIdx.x;
  int kc = blockIdx.x, m = blockIdx.z;
  int ti = blockIdx.y >> 1, tj = blockIdx.y & 1;
  const unsigned short* Xh = sp + (size_t)m * 2 * (size_t)CN;
  const unsigned short* Xl = Xh + CN;
  int v0 = ti * 128, u0 = tj * 128;
  int wave = t >> 6, lane = t & 63;
  int wv = wave >> 1, wu = wave & 1;
  int lx16 = lane & 15, quad = lane >> 4;
  int srow = t >> 2, sseg = (t & 3) * 8;
  f32x4 acc[2][4];
#pragma unroll
  for (int i = 0; i < 2; i++)
#pragma unroll
    for (int j = 0; j < 4; j++) acc[i][j] = (f32x4){0.f, 0.f, 0.f, 0.f};

  int kbeg = kc * (N_ / KSPLIT), kend = kbeg + (N_ / KSPLIT);
  for (int k0 = kbeg; k0 < kend; k0 += 32) {
    __syncthreads();
    {
      size_t goA = (size_t)(v0 + srow) * N_ + k0 + sseg;
      size_t goB = (size_t)(u0 + srow) * N_ + k0 + sseg;
      int lo_ = srow * LSTR + sseg;
      *(float4*)&sm[0*P + lo_] = *(const float4*)&Xh[goA];
      *(float4*)&sm[1*P + lo_] = *(const float4*)&Xl[goA];
      *(float4*)&sm[2*P + lo_] = *(const float4*)&Xh[goB];
      *(float4*)&sm[3*P + lo_] = *(const float4*)&Xl[goB];
    }
    __syncthreads();
#pragma unroll
    for (int mt = 0; mt < 2; mt++) {
      int arow = (wv*32 + mt*16 + lx16)*LSTR + quad*8;
      f16x8 ah = *(const f16x8*)&sm[0*P + arow];
      f16x8 al = *(const f16x8*)&sm[1*P + arow];
#pragma unroll
      for (int nt = 0; nt < 4; nt++) {
        int brow = (wu*64 + nt*16 + lx16)*LSTR + quad*8;
        f16x8 bh = *(const f16x8*)&sm[2*P + brow];
        f16x8 bl = *(const f16x8*)&sm[3*P + brow];
        f32x4 a = acc[mt][nt];
        a = __builtin_amdgcn_mfma_f32_16x16x32_f16(ah, bh, a, 0, 0, 0);
        a = __builtin_amdgcn_mfma_f32_16x16x32_f16(ah, bl, a, 0, 0, 0);
        a = __builtin_amdgcn_mfma_f32_16x16x32_f16(al, bh, a, 0, 0, 0);
        acc[mt][nt] = a;
      }
    }
  }
  float* O = covp + ((size_t)kc*4 + m) * 65536;
#pragma unroll
  for (int mt = 0; mt < 2; mt++)
#pragma unroll
    for (int nt = 0; nt < 4; nt++)
#pragma unroll
      for (int i = 0; i < 4; i++)
        O[(size_t)(v0 + wv*32 + mt*16 + quad*4 + i)*C_ + (u0 + wu*64 + nt*16 + lx16)] =
            acc[mt][nt][i];
}

// ---------------- trace from partials -> cnrm = (tr/256)*1.3 ----------------
__global__ __launch_bounds__(256) void k_trace2(const float* covp, const float* means,
                                                float* cnrm) {
  int m = blockIdx.x, t = threadIdx.x;
  float s = 0.f;
#pragma unroll
  for (int kc = 0; kc < KSPLIT; kc++)
    s += covp[((size_t)kc*4 + m)*65536 + (size_t)t*257];
  float mi = means[m*C_ + t];
  float d = (s - (float)N_*mi*mi) * (1.f/(float)(N_-1));
  __shared__ float red[256];
  red[t] = d; __syncthreads();
  for (int off = 128; off > 0; off >>= 1) { if (t < off) red[t] += red[t + off]; __syncthreads(); }
  if (!t) cnrm[m] = red[0] * (1.3f/256.f);
}

// ---------------- merged covred + nsinit ----------------
__global__ __launch_bounds__(256) void k_covred_init(const float* covp, const float* means,
                                                     const float* cnrm, float* Y, float* Z) {
  int i = blockIdx.x, m = blockIdx.y, j = threadIdx.x;
  float s = 0.f;
#pragma unroll
  for (int kc = 0; kc < KSPLIT; kc++)
    s += covp[((size_t)kc*4 + m)*65536 + (size_t)i*C_ + j];
  float mi = means[m*C_ + i], mj = means[m*C_ + j];
  float cv = (s - (float)N_*mi*mj) * (1.f/(float)(N_-1));
  size_t o = (size_t)m*65536 + (size_t)i*C_ + j;
  Y[o] = cv / cnrm[m];
  Z[o] = (i == j) ? 1.f : 0.f;
}

// ---------------- NS phase A (MFMA): T = 3I - Z·Y^T ----------------
// All NS iterates are polynomials in Y0 (Z0=I) -> symmetric & commuting, so Z·Y^T == Z·Y
// up to fp rounding (self-corrected by later iterations).
__global__ __launch_bounds__(256) void k_nsA(const float* Zin, const float* Yin, float* T) {
  __shared__ unsigned short sm[4*64*LSTR];
  int m = blockIdx.y;
  int m0 = (blockIdx.x >> 2) * 64, n0 = (blockIdx.x & 3) * 64;
  const float* A = Zin + (size_t)m*65536;
  const float* B = Yin + (size_t)m*65536;
  float* O = T + (size_t)m*65536;
  f32x4 acc[2][2];
  mm64_3term(sm, A, B, m0, n0, acc);
  int t = threadIdx.x, lane = t & 63;
  int wv = (t >> 7) & 1, wu = (t >> 6) & 1, lx16 = lane & 15, quad = lane >> 4;
#pragma unroll
  for (int mt = 0; mt < 2; mt++)
#pragma unroll
    for (int nt = 0; nt < 2; nt++)
#pragma unroll
      for (int i = 0; i < 4; i++) {
        int r = m0 + wv*32 + mt*16 + quad*4 + i;
        int c = n0 + wu*32 + nt*16 + lx16;
        float v = acc[mt][nt][i];
        O[(size_t)r*256 + c] = (r == c) ? 3.f - v : -v;
      }
}

// ---------------- NS phase B (MFMA): z=0: Y'=0.5·Y·T^T ; z=1: Z'=0.5·Z·T^T (==0.5·T·Z) ----
__global__ __launch_bounds__(256) void k_nsB(const float* Yin, const float* Zin, const float* T,
                                             float* Yout, float* Zout) {
  __shared__ unsigned short sm[4*64*LSTR];
  int m = blockIdx.y, z = blockIdx.z;
  const float* A = (z == 0 ? Yin : Zin) + (size_t)m*65536;
  const float* B = T + (size_t)m*65536;
  float* O = (z == 0 ? Yout : Zout) + (size_t)m*65536;
  int m0 = (blockIdx.x >> 2) * 64, n0 = (blockIdx.x & 3) * 64;
  f32x4 acc[2][2];
  mm64_3term(sm, A, B, m0, n0, acc);
  int t = threadIdx.x, lane = t & 63;
  int wv = (t >> 7) & 1, wu = (t >> 6) & 1, lx16 = lane & 15, quad = lane >> 4;
#pragma unroll
  for (int mt = 0; mt < 2; mt++)
#pragma unroll
    for (int nt = 0; nt < 2; nt++)
#pragma unroll
      for (int i = 0; i < 4; i++) {
        int r = m0 + wv*32 + mt*16 + quad*4 + i;
        int c = n0 + wu*32 + nt*16 + lx16;
        O[(size_t)r*256 + c] = 0.5f * acc[mt][nt][i];
      }
}

// ---------------- whiten ----------------
__global__ __launch_bounds__(256) void k_whiten(const float* content, const float* style,
                                                const float* Zall, const float* means,
                                                const float* cnrm, float* nc, float* ns) {
  int m = blockIdx.z;
  const float* x = (m < 2 ? content : style) + (size_t)(m & 1) * CN;
  float* outp = (m < 2 ? nc : ns) + (size_t)(m & 1) * CN;
  const float* Zm = Zall + (size_t)m*65536;
  const float* mean = means + m*C_;
  __shared__ float As[16][68], Bs[16][64];
  int t = threadIdx.x, tx = t & 15, ty = t >> 4;
  int n0 = blockIdx.x * 64, m0 = blockIdx.y * 64;
  float acc[4][4] = {};
  for (int k0 = 0; k0 < 256; k0 += 16) {
#pragma unroll
    for (int l = 0; l < 4; l++) {
      int e = t + l*256;
      { int kk = e & 15, mm = e >> 4; As[kk][mm] = Zm[(size_t)(m0+mm)*256 + k0+kk]; }
      { int nn = e & 63, kk = e >> 6;
        Bs[kk][nn] = x[(size_t)(k0+kk)*N_ + n0+nn] - mean[k0+kk]; }
    }
    __syncthreads();
#pragma unroll
    for (int kk = 0; kk < 16; kk++) {
      float4 b = *(const float4*)&Bs[kk][tx*4];
      fma16(acc, As[kk][ty*4+0], As[kk][ty*4+1], As[kk][ty*4+2], As[kk][ty*4+3], b);
    }
    __syncthreads();
  }
  float scale = 1.0f / sqrtf(cnrm[m]);
#pragma unroll
  for (int i = 0; i < 4; i++) {
    float4 o = make_float4(acc[i][0]*scale, acc[i][1]*scale, acc[i][2]*scale, acc[i][3]*scale);
    *(float4*)&outp[(size_t)(m0+ty*4+i)*N_ + n0 + tx*4] = o;
  }
}

// ---------------- per-pixel channel sum-of-squares of ns ----------------
__global__ __launch_bounds__(256) void k_ssq(const float* ns, float* ssq) {
  int b = blockIdx.y; int p = blockIdx.x * 256 + threadIdx.x;
  float acc = 0.f;
  for (int c = 0; c < C_; c++) { float v = ns[(size_t)b*CN + (size_t)c*N_ + p]; acc += v*v; }
  ssq[b*N_ + p] = acc;
}

// ---------------- patch reciprocal norms ----------------
__global__ __launch_bounds__(256) void k_rnorm(const float* ssq, float* rnorm) {
  int b = blockIdx.y; int s = blockIdx.x * 256 + threadIdx.x;
  int sy = s >> 6, sx = s & 63;
  float sum = 0.f;
#pragma unroll
  for (int ky = 0; ky < 3; ky++)
#pragma unroll
    for (int kx = 0; kx < 3; kx++)
      sum += ssq[b*N_ + refl(sy+ky-1)*64 + refl(sx+kx-1)];
  rnorm[b*N_ + s] = 1.f / (sqrtf(sum) + EPSF);
}

// ---------------- transpose + 2-way fp16 split for ONE batch: [c][v] -> [v][c] h/l ----------------
__global__ __launch_bounds__(256) void k_split(const float* nc_b, const float* ns_b,
                                               unsigned short* ncTh, unsigned short* ncTl,
                                               unsigned short* nsTh, unsigned short* nsTl) {
  int w = blockIdx.z;
  const float* src = w ? ns_b : nc_b;
  unsigned short* dh = w ? nsTh : ncTh;
  unsigned short* dl = w ? nsTl : ncTl;
  int u0 = blockIdx.x * 32, c0 = blockIdx.y * 32;
  __shared__ float tile[32][33];
  int t = threadIdx.x;
#pragma unroll
  for (int l = 0; l < 4; l++) {
    int e = t + l*256; int cc = e >> 5, uu = e & 31;
    tile[cc][uu] = src[(size_t)(c0+cc)*N_ + u0+uu];
  }
  __syncthreads();
#pragma unroll
  for (int l = 0; l < 4; l++) {
    int e = t + l*256; int uu = e >> 5, cc = e & 31;
    float v = tile[cc][uu];
    unsigned short h = f2h(v);
    float r1 = v - h2f(h);
    unsigned short lo = f2h(r1);
    size_t o = (size_t)(u0+uu)*C_ + c0+cc;
    dh[o] = h; dl[o] = lo;
  }
}

// ---------------- Gram via 2-way-split fp16 MFMA + fused x-blur ----------------
// Round-2 geometry (LSTR=40, K-step 32, LDS 40960 -> 3 blocks/CU) + round-4's hoisted
// fragment loads (12 b128 reads then 24 MFMAs per k32, was 20 reads unhoisted).
__global__ __launch_bounds__(512) void k_gram(const unsigned short* Ah_g, const unsigned short* Al_g,
                                              const unsigned short* Bh_g, const unsigned short* Bl_g,
                                              float* Hx) {
  __shared__ unsigned short sm[4*128*LSTR];  // 40960 B; epilogue Gs[64][133] fp32 unioned
  const int P = 128*LSTR;
  int t = threadIdx.x;
  int v0 = blockIdx.y * 128, u0 = blockIdx.x * 128;
  int wave = t >> 6, lane = t & 63;
  int wv = wave >> 1, wu = wave & 1;
  int lx16 = lane & 15, quad = lane >> 4;
  int srow = t >> 2, sseg = (t & 3) * 8;     // 512 thr = 128 rows x 4 segs of 8 ushort (16 B)
  f32x4 acc[2][4];
#pragma unroll
  for (int i = 0; i < 2; i++)
#pragma unroll
    for (int j = 0; j < 4; j++) acc[i][j] = (f32x4){0.f, 0.f, 0.f, 0.f};

  for (int k0 = 0; k0 < 256; k0 += 32) {
    __syncthreads();
    {
      size_t goA = (size_t)(v0 + srow)*C_ + k0 + sseg;
      size_t goB = (size_t)(u0 + srow)*C_ + k0 + sseg;
      int lo_ = srow*LSTR + sseg;
      *(float4*)&sm[0*P + lo_] = *(const float4*)&Ah_g[goA];
      *(float4*)&sm[1*P + lo_] = *(const float4*)&Al_g[goA];
      *(float4*)&sm[2*P + lo_] = *(const float4*)&Bh_g[goB];
      *(float4*)&sm[3*P + lo_] = *(const float4*)&Bl_g[goB];
    }
    __syncthreads();
    int kb = quad*8;
    f16x8 ah[2], al[2];
#pragma unroll
    for (int mt = 0; mt < 2; mt++) {
      int arow = (wv*32 + mt*16 + lx16)*LSTR + kb;
      ah[mt] = *(const f16x8*)&sm[0*P + arow];
      al[mt] = *(const f16x8*)&sm[1*P + arow];
    }
    f16x8 bh[4], bl[4];
#pragma unroll
    for (int nt = 0; nt < 4; nt++) {
      int brow = (wu*64 + nt*16 + lx16)*LSTR + kb;
      bh[nt] = *(const f16x8*)&sm[2*P + brow];
      bl[nt] = *(const f16x8*)&sm[3*P + brow];
    }
#pragma unroll
    for (int mt = 0; mt < 2; mt++)
#pragma unroll
      for (int nt = 0; nt < 4; nt++) {
        f32x4 a = acc[mt][nt];
        a = __builtin_amdgcn_mfma_f32_16x16x32_f16(ah[mt], bh[nt], a, 0, 0, 0);
        a = __builtin_amdgcn_mfma_f32_16x16x32_f16(ah[mt], bl[nt], a, 0, 0, 0);
        a = __builtin_amdgcn_mfma_f32_16x16x32_f16(al[mt], bh[nt], a, 0, 0, 0);
        acc[mt][nt] = a;
      }
  }
  // epilogue: per 64-row half h, x-diagonal blur. Gs stride 133 fp32.
  float* Gs = (float*)sm;
  int btx = t & 15, bty = t >> 4;            // bty 0..31
#pragma unroll
  for (int h = 0; h < 2; h++) {
    __syncthreads();
    if ((wv >> 1) == h) {                    // waves with wv in {2h,2h+1} own rows h*64..+63
      int rbase = (wv & 1) * 32;
#pragma unroll
      for (int mt = 0; mt < 2; mt++)
#pragma unroll
        for (int nt = 0; nt < 4; nt++)
#pragma unroll
          for (int i = 0; i < 4; i++)
            Gs[(rbase + mt*16 + quad*4 + i)*133 + wu*64 + nt*16 + lx16] = acc[mt][nt][i];
    }
    __syncthreads();
#pragma unroll
    for (int i = 0; i < 2; i++) {
      int px = bty*2 + i;
      int xm = refl(px-1), xp = refl(px+1);
#pragma unroll
      for (int jh = 0; jh < 2; jh++) {
        int ub = jh*64;
        float tmp[4];
#pragma unroll
        for (int j = 0; j < 4; j++) {
          int sx = btx*4 + j;
          int smm = refl(sx-1), sp = refl(sx+1);
          tmp[j] = Gs[xm*133 + ub + smm] + Gs[px*133 + ub + sx] + Gs[xp*133 + ub + sp];
        }
        *(float4*)&Hx[(size_t)(v0 + h*64 + px)*N_ + u0 + ub + btx*4] =
            make_float4(tmp[0], tmp[1], tmp[2], tmp[3]);
      }
    }
  }
}

// ---------------- y-diagonal blur of Hx + argmax (round-2 natural order) ----------------
__global__ __launch_bounds__(256) void k_argmax(const float* Hx, const float* rnorm,
                                                int* idx, int b) {
  int p = blockIdx.x, t = threadIdx.x;
  int py = p >> 6, px = p & 63;
  size_t r0 = (size_t)(refl(py-1)*64 + px) * N_;
  size_t r1 = (size_t)p * N_;
  size_t r2 = (size_t)(refl(py+1)*64 + px) * N_;
  float bv = -1e30f; int bs = 0;
  for (int s = t; s < N_; s += 256) {
    int sy = s >> 6, sx = s & 63;
    int u0 = refl(sy-1)*64 + sx, u2 = refl(sy+1)*64 + sx;
    float acc = Hx[r0 + u0] + Hx[r1 + s] + Hx[r2 + u2];
    float sc = acc * rnorm[b*N_ + s];
    if (sc > bv) { bv = sc; bs = s; }
  }
  __shared__ float sv[256]; __shared__ int si[256];
  sv[t] = bv; si[t] = bs; __syncthreads();
  for (int off = 128; off > 0; off >>= 1) {
    if (t < off) {
      if (sv[t+off] > sv[t] || (sv[t+off] == sv[t] && si[t+off] < si[t])) {
        sv[t] = sv[t+off]; si[t] = si[t+off];
      }
    }
    __syncthreads();
  }
  if (!t) idx[b*N_ + p] = si[0];
}

// ---------------- deconv gather for batch b: recont_b[p][c] from fp16 pair ----------------
__global__ __launch_bounds__(256) void k_recon(const unsigned short* nsTh,
                                               const unsigned short* nsTl,
                                               const int* idx_b, float* recont_b) {
  int p = blockIdx.x, c = threadIdx.x;
  int py = p >> 6, px = p & 63;
  float acc = 0.f;
#pragma unroll
  for (int dy = 0; dy < 3; dy++)
#pragma unroll
    for (int dx = 0; dx < 3; dx++) {
      int q = refl(py+dy-1)*64 + refl(px+dx-1);
      int s = idx_b[q];
      int sy = s >> 6, sx = s & 63;
      size_t o = (size_t)(refl(sy+1-dy)*64 + refl(sx+1-dx))*C_ + c;
      acc += h2f(nsTh[o]) + h2f(nsTl[o]);
    }
  float dc = ((py==0||py==63)?2.f:3.f) * ((px==0||px==63)?2.f:3.f);
  recont_b[(size_t)p*C_ + c] = acc / dc;
}

// ---------------- coloring (MFMA): out = Ym·recont^T (recont already [n][k]) ----------------
__global__ __launch_bounds__(256) void k_color(const float* Yall, const float* recont_all,
                                               const float* cnrm, const float* means,
                                               float* out_all) {
  __shared__ unsigned short sm[4*64*LSTR];
  int b = blockIdx.z;
  const float* Ym = Yall + (size_t)(2+b)*65536;
  const float* recont = recont_all + (size_t)b*CN;   // [4096][256]
  const float* smean = means + (2+b)*C_;
  float* out = out_all + (size_t)b*CN;               // [256][4096]
  int m0 = blockIdx.y * 64;
  int n0 = blockIdx.x * 64;
  f32x4 acc[2][2];
  mm64_3term(sm, Ym, recont, m0, n0, acc);
  float scale = sqrtf(cnrm[2+b]);
  int t = threadIdx.x, lane = t & 63;
  int wv = (t >> 7) & 1, wu = (t >> 6) & 1, lx16 = lane & 15, quad = lane >> 4;
#pragma unroll
  for (int mt = 0; mt < 2; mt++)
#pragma unroll
    for (int nt = 0; nt < 2; nt++)
#pragma unroll
      for (int i = 0; i < 4; i++) {
        int r = m0 + wv*32 + mt*16 + quad*4 + i;
        int c = n0 + wu*32 + nt*16 + lx16;
        out[(size_t)r*N_ + c] = acc[mt][nt][i]*scale + smean[r];
      }
}

extern "C" void kernel_launch(void* const* d_in, const int* in_sizes, int n_in,
                              void* d_out, int out_size, void* d_ws, size_t ws_size,
                              hipStream_t stream) {
  const float* content = (const float*)d_in[0];
  const float* style   = (const float*)d_in[1];
  float* out = (float*)d_out;

  // workspace layout (floats); total ~102 MiB
  float* F = (float*)d_ws;
  float* means  = F + 0;         // 4*256
  float* cnrm   = F + 1024;      // 4
  float* Y      = F + 264192;    // NS buffers
  float* Z      = F + 526336;
  float* Y2     = F + 788480;
  float* Z2     = F + 1050624;
  float* T      = F + 1312768;
  float* nc     = F + 1574912;   // 2*CN fp32 (dead after split(1))
  float* ns     = F + 3672064;   // 2*CN fp32 (dead after split(1))
  float* nstslot= F + 5769216;   // 2*CN floats = 4 fp16 plane slots
  float* recont = F + 7866368;   // 2*CN fp32
  float* ssq    = F + 9963520;   // 2*4096
  float* rnorm  = F + 9971712;   // 2*4096
  int*   idx    = (int*)(F + 9979904); // 2*4096
  float* Hx     = F + 9988096;   // 4096*4096

  // cov-phase aliases inside Hx (dead until k_gram at step 8)
  unsigned short* covsp = (unsigned short*)Hx;
  float* covp = Hx + 2*(size_t)CN*2;   // = Hx + 4194304 floats

  unsigned short* nsTh = (unsigned short*)nstslot;
  unsigned short* nsTl = (unsigned short*)nstslot + (size_t)CN;
  unsigned short* ncTh = (unsigned short*)nstslot + 2*(size_t)CN;
  unsigned short* ncTl = (unsigned short*)nstslot + 3*(size_t)CN;

  // 1-4. means, fp16-split, MFMA cov partials, trace, covred+nsinit
  k_mean<<<dim3(256,4), 256, 0, stream>>>(content, style, means);
  k_splitcov<<<dim3(1024,4), 256, 0, stream>>>(content, style, covsp);
  k_covmm<<<dim3(KSPLIT,4,4), 512, 0, stream>>>(covsp, covp);
  k_trace2<<<4, 256, 0, stream>>>(covp, means, cnrm);
  k_covred_init<<<dim3(256,4), 256, 0, stream>>>(covp, means, cnrm, Y, Z);
  // 5. NS iterations (MFMA)
  float *Ya = Y, *Za = Z, *Yb = Y2, *Zb = Z2;
  for (int it = 0; it < NS_ITERS; it++) {
    k_nsA<<<dim3(16,4), 256, 0, stream>>>(Za, Ya, T);
    k_nsB<<<dim3(16,4,2), 256, 0, stream>>>(Ya, Za, T, Yb, Zb);
    float* tmp;
    tmp = Ya; Ya = Yb; Yb = tmp;
    tmp = Za; Za = Zb; Zb = tmp;
  }
  // 6. whitening
  k_whiten<<<dim3(64,4,4), 256, 0, stream>>>(content, style, Za, means, cnrm, nc, ns);
  // 7. patch norms
  k_ssq<<<dim3(16,2), 256, 0, stream>>>(ns, ssq);
  k_rnorm<<<dim3(16,2), 256, 0, stream>>>(ssq, rnorm);
  // 8. per batch: split -> MFMA gram + x-blur -> y-blur+argmax -> recon
  for (int b = 0; b < 2; b++) {
    k_split<<<dim3(128,8,2), 256, 0, stream>>>(nc + (size_t)b*CN, ns + (size_t)b*CN,
                                               ncTh, ncTl, nsTh, nsTl);
    k_gram<<<dim3(32,32), 512, 0, stream>>>(ncTh, ncTl, nsTh, nsTl, Hx);
    k_argmax<<<4096, 256, 0, stream>>>(Hx, rnorm, idx, b);
    k_recon<<<4096, 256, 0, stream>>>(nsTh, nsTl, idx + (size_t)b*N_,
                                      recont + (size_t)b*CN);
  }
  // 9. coloring (MFMA)
  k_color<<<dim3(64,4,2), 256, 0, stream>>>(Ya, recont, cnrm, means, out);
}

// Round 6
// 376.177 us; speedup vs baseline: 1.3645x; 1.0740x over previous
//
#include <hip/hip_runtime.h>
#include <hip/hip_bf16.h>

#define C_ 256
#define N_ 4096
#define CN (C_*N_)
#define EPSF 1e-5f
#define NS_ITERS 6
#define KSPLIT 16  // split-K for MFMA cov partials
#define LSTR 40   // LDS row stride in ushort (80 B, 16B-aligned)

typedef _Float16 f16x8 __attribute__((ext_vector_type(8)));
typedef float f32x4 __attribute__((ext_vector_type(4)));

__device__ __forceinline__ int refl(int t) {
  return t < 0 ? -t : (t > 63 ? 126 - t : t);
}

// fp16 2-way split: v = h + l exact to ~2^-22 rel. Products hh+hl+lh drop only ll
// ~2^-22 rel — below the fp32 reference's own accumulation noise.
__device__ __forceinline__ unsigned short f2h(float x) {
  _Float16 h = (_Float16)x;
  return __builtin_bit_cast(unsigned short, h);
}
__device__ __forceinline__ float h2f(unsigned short u) {
  return (float)__builtin_bit_cast(_Float16, u);
}

// ---------------- shared MFMA helper: 64x64 out tile of A·B^T, K=256, fp32 in ----------------
// On-the-fly fp16 h/l split during staging; 3-term MFMA (hh+hl+lh). 256 thr = 4 waves.
// Valid for NS (iterates symmetric+commuting) and color (recont already [n][k]).
__device__ __forceinline__ void mm64_3term(unsigned short* sm, const float* A, const float* B,
                                           int m0, int n0, f32x4 acc[2][2]) {
  const int P = 64*LSTR;
  int t = threadIdx.x;
  int lane = t & 63;
  int wv = (t >> 7) & 1, wu = (t >> 6) & 1;
  int lx16 = lane & 15, quad = lane >> 4;
  int srow = t >> 2, sseg = (t & 3) * 8;    // 256 thr = 64 rows x 4 segs of 8 floats
#pragma unroll
  for (int i = 0; i < 2; i++)
#pragma unroll
    for (int j = 0; j < 2; j++) acc[i][j] = (f32x4){0.f, 0.f, 0.f, 0.f};
  for (int k0 = 0; k0 < 256; k0 += 32) {
    __syncthreads();
    {
      const float* pa = &A[(size_t)(m0 + srow)*256 + k0 + sseg];
      const float* pb = &B[(size_t)(n0 + srow)*256 + k0 + sseg];
#pragma unroll
      for (int g = 0; g < 2; g++) {
        float4 va = *(const float4*)(pa + g*4);
        float4 vb = *(const float4*)(pb + g*4);
        float fa[4] = {va.x, va.y, va.z, va.w};
        float fb[4] = {vb.x, vb.y, vb.z, vb.w};
        unsigned short ha[4], la[4], hb[4], lb[4];
#pragma unroll
        for (int j = 0; j < 4; j++) {
          unsigned short h = f2h(fa[j]); ha[j] = h; la[j] = f2h(fa[j] - h2f(h));
          h = f2h(fb[j]); hb[j] = h; lb[j] = f2h(fb[j] - h2f(h));
        }
        int lo_ = srow*LSTR + sseg + g*4;
        *(ushort4*)&sm[0*P + lo_] = make_ushort4(ha[0], ha[1], ha[2], ha[3]);
        *(ushort4*)&sm[1*P + lo_] = make_ushort4(la[0], la[1], la[2], la[3]);
        *(ushort4*)&sm[2*P + lo_] = make_ushort4(hb[0], hb[1], hb[2], hb[3]);
        *(ushort4*)&sm[3*P + lo_] = make_ushort4(lb[0], lb[1], lb[2], lb[3]);
      }
    }
    __syncthreads();
    f16x8 ah[2], al[2], bh[2], bl[2];
#pragma unroll
    for (int mt = 0; mt < 2; mt++) {
      int arow = (wv*32 + mt*16 + lx16)*LSTR + quad*8;
      ah[mt] = *(const f16x8*)&sm[0*P + arow];
      al[mt] = *(const f16x8*)&sm[1*P + arow];
    }
#pragma unroll
    for (int nt = 0; nt < 2; nt++) {
      int brow = (wu*32 + nt*16 + lx16)*LSTR + quad*8;
      bh[nt] = *(const f16x8*)&sm[2*P + brow];
      bl[nt] = *(const f16x8*)&sm[3*P + brow];
    }
#pragma unroll
    for (int mt = 0; mt < 2; mt++)
#pragma unroll
      for (int nt = 0; nt < 2; nt++) {
        f32x4 a = acc[mt][nt];
        a = __builtin_amdgcn_mfma_f32_16x16x32_f16(ah[mt], bh[nt], a, 0, 0, 0);
        a = __builtin_amdgcn_mfma_f32_16x16x32_f16(ah[mt], bl[nt], a, 0, 0, 0);
        a = __builtin_amdgcn_mfma_f32_16x16x32_f16(al[mt], bh[nt], a, 0, 0, 0);
        acc[mt][nt] = a;
      }
  }
}

// ---------------- means ----------------
__global__ __launch_bounds__(256) void k_mean(const float* content, const float* style,
                                              float* means) {
  int c = blockIdx.x, m = blockIdx.y, t = threadIdx.x;
  const float* x = (m < 2 ? content : style) + (size_t)(m & 1) * CN + (size_t)c * N_;
  float s = 0.f;
  for (int i = t; i < N_; i += 256) s += x[i];
  __shared__ float red[256];
  red[t] = s; __syncthreads();
  for (int off = 128; off > 0; off >>= 1) { if (t < off) red[t] += red[t + off]; __syncthreads(); }
  if (t == 0) means[m * C_ + c] = red[0] * (1.f / N_);
}

// ---------------- fused split: raw [c][n] planes for cov + mean-sub transposed [v][c] planes ----
// Per 32x32 tile of matrix m: phase 1 loads (vectorized), writes covsp h/l (raw) and
// stages tile; phase 2 writes xcT h/l ([v][c], mean-subtracted).
__global__ __launch_bounds__(256) void k_splitall(const float* content, const float* style,
                                                  const float* means,
                                                  unsigned short* covsp, unsigned short* xcT) {
  int m = blockIdx.z;
  const float* x = (m < 2 ? content : style) + (size_t)(m & 1) * CN;
  int u0 = blockIdx.x * 32, c0 = blockIdx.y * 32;
  unsigned short* ch_ = covsp + (size_t)(2*m+0)*CN;
  unsigned short* cl_ = covsp + (size_t)(2*m+1)*CN;
  unsigned short* th_ = xcT + (size_t)(2*m+0)*CN;
  unsigned short* tl_ = xcT + (size_t)(2*m+1)*CN;
  __shared__ float tile[32][33];
  int t = threadIdx.x;
  {
    int cc = t >> 3, uu4 = (t & 7) * 4;
    float4 v = *(const float4*)&x[(size_t)(c0+cc)*N_ + u0 + uu4];
    float f[4] = {v.x, v.y, v.z, v.w};
    unsigned short h[4], lo[4];
#pragma unroll
    for (int j = 0; j < 4; j++) {
      unsigned short hh = f2h(f[j]);
      h[j] = hh; lo[j] = f2h(f[j] - h2f(hh));
      tile[cc][uu4+j] = f[j];
    }
    size_t o = (size_t)(c0+cc)*N_ + u0 + uu4;
    *(ushort4*)&ch_[o] = make_ushort4(h[0], h[1], h[2], h[3]);
    *(ushort4*)&cl_[o] = make_ushort4(lo[0], lo[1], lo[2], lo[3]);
  }
  __syncthreads();
  {
    int uu = t >> 3, cc4 = (t & 7) * 4;
    unsigned short h[4], lo[4];
#pragma unroll
    for (int j = 0; j < 4; j++) {
      float v = tile[cc4+j][uu] - means[m*C_ + c0 + cc4 + j];
      unsigned short hh = f2h(v);
      h[j] = hh; lo[j] = f2h(v - h2f(hh));
    }
    size_t o = (size_t)(u0+uu)*C_ + c0 + cc4;
    *(ushort4*)&th_[o] = make_ushort4(h[0], h[1], h[2], h[3]);
    *(ushort4*)&tl_[o] = make_ushort4(lo[0], lo[1], lo[2], lo[3]);
  }
}

// ---------------- covariance raw sums via 3-term fp16 MFMA, split-K ----------------
__global__ __launch_bounds__(512) void k_covmm(const unsigned short* sp, float* covp) {
  __shared__ unsigned short sm[4*128*LSTR];   // 40960 B
  const int P = 128*LSTR;
  int t = threadIdx.x;
  int kc = blockIdx.x, m = blockIdx.z;
  int ti = blockIdx.y >> 1, tj = blockIdx.y & 1;
  const unsigned short* Xh = sp + (size_t)m * 2 * (size_t)CN;
  const unsigned short* Xl = Xh + CN;
  int v0 = ti * 128, u0 = tj * 128;
  int wave = t >> 6, lane = t & 63;
  int wv = wave >> 1, wu = wave & 1;
  int lx16 = lane & 15, quad = lane >> 4;
  int srow = t >> 2, sseg = (t & 3) * 8;
  f32x4 acc[2][4];
#pragma unroll
  for (int i = 0; i < 2; i++)
#pragma unroll
    for (int j = 0; j < 4; j++) acc[i][j] = (f32x4){0.f, 0.f, 0.f, 0.f};

  int kbeg = kc * (N_ / KSPLIT), kend = kbeg + (N_ / KSPLIT);
  for (int k0 = kbeg; k0 < kend; k0 += 32) {
    __syncthreads();
    {
      size_t goA = (size_t)(v0 + srow) * N_ + k0 + sseg;
      size_t goB = (size_t)(u0 + srow) * N_ + k0 + sseg;
      int lo_ = srow * LSTR + sseg;
      *(float4*)&sm[0*P + lo_] = *(const float4*)&Xh[goA];
      *(float4*)&sm[1*P + lo_] = *(const float4*)&Xl[goA];
      *(float4*)&sm[2*P + lo_] = *(const float4*)&Xh[goB];
      *(float4*)&sm[3*P + lo_] = *(const float4*)&Xl[goB];
    }
    __syncthreads();
#pragma unroll
    for (int mt = 0; mt < 2; mt++) {
      int arow = (wv*32 + mt*16 + lx16)*LSTR + quad*8;
      f16x8 ah = *(const f16x8*)&sm[0*P + arow];
      f16x8 al = *(const f16x8*)&sm[1*P + arow];
#pragma unroll
      for (int nt = 0; nt < 4; nt++) {
        int brow = (wu*64 + nt*16 + lx16)*LSTR + quad*8;
        f16x8 bh = *(const f16x8*)&sm[2*P + brow];
        f16x8 bl = *(const f16x8*)&sm[3*P + brow];
        f32x4 a = acc[mt][nt];
        a = __builtin_amdgcn_mfma_f32_16x16x32_f16(ah, bh, a, 0, 0, 0);
        a = __builtin_amdgcn_mfma_f32_16x16x32_f16(ah, bl, a, 0, 0, 0);
        a = __builtin_amdgcn_mfma_f32_16x16x32_f16(al, bh, a, 0, 0, 0);
        acc[mt][nt] = a;
      }
    }
  }
  float* O = covp + ((size_t)kc*4 + m) * 65536;
#pragma unroll
  for (int mt = 0; mt < 2; mt++)
#pragma unroll
    for (int nt = 0; nt < 4; nt++)
#pragma unroll
      for (int i = 0; i < 4; i++)
        O[(size_t)(v0 + wv*32 + mt*16 + quad*4 + i)*C_ + (u0 + wu*64 + nt*16 + lx16)] =
            acc[mt][nt][i];
}

// ---------------- trace from partials -> cnrm = (tr/256)*1.3 ----------------
__global__ __launch_bounds__(256) void k_trace2(const float* covp, const float* means,
                                                float* cnrm) {
  int m = blockIdx.x, t = threadIdx.x;
  float s = 0.f;
#pragma unroll
  for (int kc = 0; kc < KSPLIT; kc++)
    s += covp[((size_t)kc*4 + m)*65536 + (size_t)t*257];
  float mi = means[m*C_ + t];
  float d = (s - (float)N_*mi*mi) * (1.f/(float)(N_-1));
  __shared__ float red[256];
  red[t] = d; __syncthreads();
  for (int off = 128; off > 0; off >>= 1) { if (t < off) red[t] += red[t + off]; __syncthreads(); }
  if (!t) cnrm[m] = red[0] * (1.3f/256.f);
}

// ---------------- merged covred + nsinit ----------------
__global__ __launch_bounds__(256) void k_covred_init(const float* covp, const float* means,
                                                     const float* cnrm, float* Y, float* Z) {
  int i = blockIdx.x, m = blockIdx.y, j = threadIdx.x;
  float s = 0.f;
#pragma unroll
  for (int kc = 0; kc < KSPLIT; kc++)
    s += covp[((size_t)kc*4 + m)*65536 + (size_t)i*C_ + j];
  float mi = means[m*C_ + i], mj = means[m*C_ + j];
  float cv = (s - (float)N_*mi*mj) * (1.f/(float)(N_-1));
  size_t o = (size_t)m*65536 + (size_t)i*C_ + j;
  Y[o] = cv / cnrm[m];
  Z[o] = (i == j) ? 1.f : 0.f;
}

// ---------------- NS phase A (MFMA): T = 3I - Z·Y^T ----------------
__global__ __launch_bounds__(256) void k_nsA(const float* Zin, const float* Yin, float* T) {
  __shared__ unsigned short sm[4*64*LSTR];
  int m = blockIdx.y;
  int m0 = (blockIdx.x >> 2) * 64, n0 = (blockIdx.x & 3) * 64;
  const float* A = Zin + (size_t)m*65536;
  const float* B = Yin + (size_t)m*65536;
  float* O = T + (size_t)m*65536;
  f32x4 acc[2][2];
  mm64_3term(sm, A, B, m0, n0, acc);
  int t = threadIdx.x, lane = t & 63;
  int wv = (t >> 7) & 1, wu = (t >> 6) & 1, lx16 = lane & 15, quad = lane >> 4;
#pragma unroll
  for (int mt = 0; mt < 2; mt++)
#pragma unroll
    for (int nt = 0; nt < 2; nt++)
#pragma unroll
      for (int i = 0; i < 4; i++) {
        int r = m0 + wv*32 + mt*16 + quad*4 + i;
        int c = n0 + wu*32 + nt*16 + lx16;
        float v = acc[mt][nt][i];
        O[(size_t)r*256 + c] = (r == c) ? 3.f - v : -v;
      }
}

// ---------------- NS phase B (MFMA) ----------------
__global__ __launch_bounds__(256) void k_nsB(const float* Yin, const float* Zin, const float* T,
                                             float* Yout, float* Zout) {
  __shared__ unsigned short sm[4*64*LSTR];
  int m = blockIdx.y, z = blockIdx.z;
  const float* A = (z == 0 ? Yin : Zin) + (size_t)m*65536;
  const float* B = T + (size_t)m*65536;
  float* O = (z == 0 ? Yout : Zout) + (size_t)m*65536;
  int m0 = (blockIdx.x >> 2) * 64, n0 = (blockIdx.x & 3) * 64;
  f32x4 acc[2][2];
  mm64_3term(sm, A, B, m0, n0, acc);
  int t = threadIdx.x, lane = t & 63;
  int wv = (t >> 7) & 1, wu = (t >> 6) & 1, lx16 = lane & 15, quad = lane >> 4;
#pragma unroll
  for (int mt = 0; mt < 2; mt++)
#pragma unroll
    for (int nt = 0; nt < 2; nt++)
#pragma unroll
      for (int i = 0; i < 4; i++) {
        int r = m0 + wv*32 + mt*16 + quad*4 + i;
        int c = n0 + wu*32 + nt*16 + lx16;
        O[(size_t)r*256 + c] = 0.5f * acc[mt][nt][i];
      }
}

// ---------------- whiten via MFMA, writing whitened TRANSPOSED fp16 planes directly ----------
// out(ch, v) = scale * sum_k Za[ch][k] * xcT[v][k]  (xcT pre-split, mean-subtracted).
// A = Za rows (fp32, split on the fly; Za symmetric so rows==cols). Epilogue: scale, split
// h/l in-register, LDS-transpose, coalesced store to outT [v][c] h/l planes.
// Replaces k_whiten + k_split entirely; nc/ns fp32 never materialized.
__global__ __launch_bounds__(256) void k_whitenT(const unsigned short* xcT, const float* Zall,
                                                 const float* cnrm, unsigned short* outT) {
  __shared__ unsigned short sm[4*64*LSTR];   // 20480 B; epilogue Th/Tl [64][72] unioned (18432)
  const int P = 64*LSTR;
  int m = blockIdx.z;
  int v0 = blockIdx.x * 64, c0 = blockIdx.y * 64;
  const float* Zm = Zall + (size_t)m*65536;
  const unsigned short* Bh_g = xcT + (size_t)(2*m+0)*CN;
  const unsigned short* Bl_g = xcT + (size_t)(2*m+1)*CN;
  unsigned short* Oh = outT + (size_t)(2*m+0)*CN;
  unsigned short* Ol = outT + (size_t)(2*m+1)*CN;
  int t = threadIdx.x, lane = t & 63;
  int wv = (t >> 7) & 1, wu = (t >> 6) & 1;
  int lx16 = lane & 15, quad = lane >> 4;
  int srow = t >> 2, sseg = (t & 3) * 8;
  f32x4 acc[2][2];
#pragma unroll
  for (int i = 0; i < 2; i++)
#pragma unroll
    for (int j = 0; j < 2; j++) acc[i][j] = (f32x4){0.f, 0.f, 0.f, 0.f};
  for (int k0 = 0; k0 < 256; k0 += 32) {
    __syncthreads();
    {
      const float* pa = &Zm[(size_t)(c0 + srow)*256 + k0 + sseg];
      int lo_ = srow*LSTR + sseg;
#pragma unroll
      for (int g = 0; g < 2; g++) {
        float4 va = *(const float4*)(pa + g*4);
        float fa[4] = {va.x, va.y, va.z, va.w};
        unsigned short ha[4], la[4];
#pragma unroll
        for (int j = 0; j < 4; j++) {
          unsigned short h = f2h(fa[j]); ha[j] = h; la[j] = f2h(fa[j] - h2f(h));
        }
        *(ushort4*)&sm[0*P + lo_ + g*4] = make_ushort4(ha[0], ha[1], ha[2], ha[3]);
        *(ushort4*)&sm[1*P + lo_ + g*4] = make_ushort4(la[0], la[1], la[2], la[3]);
      }
      size_t gb = (size_t)(v0 + srow)*C_ + k0 + sseg;
      *(float4*)&sm[2*P + lo_] = *(const float4*)&Bh_g[gb];
      *(float4*)&sm[3*P + lo_] = *(const float4*)&Bl_g[gb];
    }
    __syncthreads();
    f16x8 ah[2], al[2], bh[2], bl[2];
#pragma unroll
    for (int mt = 0; mt < 2; mt++) {
      int arow = (wv*32 + mt*16 + lx16)*LSTR + quad*8;
      ah[mt] = *(const f16x8*)&sm[0*P + arow];
      al[mt] = *(const f16x8*)&sm[1*P + arow];
    }
#pragma unroll
    for (int nt = 0; nt < 2; nt++) {
      int brow = (wu*32 + nt*16 + lx16)*LSTR + quad*8;
      bh[nt] = *(const f16x8*)&sm[2*P + brow];
      bl[nt] = *(const f16x8*)&sm[3*P + brow];
    }
#pragma unroll
    for (int mt = 0; mt < 2; mt++)
#pragma unroll
      for (int nt = 0; nt < 2; nt++) {
        f32x4 a = acc[mt][nt];
        a = __builtin_amdgcn_mfma_f32_16x16x32_f16(ah[mt], bh[nt], a, 0, 0, 0);
        a = __builtin_amdgcn_mfma_f32_16x16x32_f16(ah[mt], bl[nt], a, 0, 0, 0);
        a = __builtin_amdgcn_mfma_f32_16x16x32_f16(al[mt], bh[nt], a, 0, 0, 0);
        acc[mt][nt] = a;
      }
  }
  // epilogue: scale, split, transpose via LDS, coalesced [v][c] store
  float scale = 1.0f / sqrtf(cnrm[m]);
  __syncthreads();
  unsigned short* Th = sm;             // [64][72]
  unsigned short* Tl = sm + 64*72;
#pragma unroll
  for (int mt = 0; mt < 2; mt++)
#pragma unroll
    for (int nt = 0; nt < 2; nt++)
#pragma unroll
      for (int i = 0; i < 4; i++) {
        int chl = wv*32 + mt*16 + quad*4 + i;
        int vl  = wu*32 + nt*16 + lx16;
        float w = acc[mt][nt][i] * scale;
        unsigned short h = f2h(w);
        unsigned short l = f2h(w - h2f(h));
        Th[vl*72 + chl] = h;
        Tl[vl*72 + chl] = l;
      }
  __syncthreads();
  int vr = t >> 2, cs = (t & 3) * 16;
  size_t go = (size_t)(v0 + vr)*C_ + c0 + cs;
  *(float4*)&Oh[go]     = *(float4*)&Th[vr*72 + cs];
  *(float4*)&Oh[go + 8] = *(float4*)&Th[vr*72 + cs + 8];
  *(float4*)&Ol[go]     = *(float4*)&Tl[vr*72 + cs];
  *(float4*)&Ol[go + 8] = *(float4*)&Tl[vr*72 + cs + 8];
}

// ---------------- per-pixel channel sum-of-squares from whitened planes ----------------
__global__ __launch_bounds__(256) void k_ssq(const unsigned short* outT, float* ssq) {
  int b = blockIdx.y; int p = blockIdx.x * 256 + threadIdx.x;
  const unsigned short* h = outT + (size_t)(2*(2+b))*CN + (size_t)p*C_;
  const unsigned short* l = h + CN;
  float acc = 0.f;
  for (int c = 0; c < C_; c += 4) {
    ushort4 hv = *(const ushort4*)&h[c];
    ushort4 lv = *(const ushort4*)&l[c];
    float v0 = h2f(hv.x) + h2f(lv.x);
    float v1 = h2f(hv.y) + h2f(lv.y);
    float v2 = h2f(hv.z) + h2f(lv.z);
    float v3 = h2f(hv.w) + h2f(lv.w);
    acc += v0*v0 + v1*v1 + v2*v2 + v3*v3;
  }
  ssq[b*N_ + p] = acc;
}

// ---------------- patch reciprocal norms ----------------
__global__ __launch_bounds__(256) void k_rnorm(const float* ssq, float* rnorm) {
  int b = blockIdx.y; int s = blockIdx.x * 256 + threadIdx.x;
  int sy = s >> 6, sx = s & 63;
  float sum = 0.f;
#pragma unroll
  for (int ky = 0; ky < 3; ky++)
#pragma unroll
    for (int kx = 0; kx < 3; kx++)
      sum += ssq[b*N_ + refl(sy+ky-1)*64 + refl(sx+kx-1)];
  rnorm[b*N_ + s] = 1.f / (sqrtf(sum) + EPSF);
}

// ---------------- Gram via 2-way-split fp16 MFMA + fused x-blur (round-5 geometry) ---------
__global__ __launch_bounds__(512) void k_gram(const unsigned short* Ah_g, const unsigned short* Al_g,
                                              const unsigned short* Bh_g, const unsigned short* Bl_g,
                                              float* Hx) {
  __shared__ unsigned short sm[4*128*LSTR];  // 40960 B; epilogue Gs[64][133] fp32 unioned
  const int P = 128*LSTR;
  int t = threadIdx.x;
  int v0 = blockIdx.y * 128, u0 = blockIdx.x * 128;
  int wave = t >> 6, lane = t & 63;
  int wv = wave >> 1, wu = wave & 1;
  int lx16 = lane & 15, quad = lane >> 4;
  int srow = t >> 2, sseg = (t & 3) * 8;
  f32x4 acc[2][4];
#pragma unroll
  for (int i = 0; i < 2; i++)
#pragma unroll
    for (int j = 0; j < 4; j++) acc[i][j] = (f32x4){0.f, 0.f, 0.f, 0.f};

  for (int k0 = 0; k0 < 256; k0 += 32) {
    __syncthreads();
    {
      size_t goA = (size_t)(v0 + srow)*C_ + k0 + sseg;
      size_t goB = (size_t)(u0 + srow)*C_ + k0 + sseg;
      int lo_ = srow*LSTR + sseg;
      *(float4*)&sm[0*P + lo_] = *(const float4*)&Ah_g[goA];
      *(float4*)&sm[1*P + lo_] = *(const float4*)&Al_g[goA];
      *(float4*)&sm[2*P + lo_] = *(const float4*)&Bh_g[goB];
      *(float4*)&sm[3*P + lo_] = *(const float4*)&Bl_g[goB];
    }
    __syncthreads();
    int kb = quad*8;
    f16x8 ah[2], al[2];
#pragma unroll
    for (int mt = 0; mt < 2; mt++) {
      int arow = (wv*32 + mt*16 + lx16)*LSTR + kb;
      ah[mt] = *(const f16x8*)&sm[0*P + arow];
      al[mt] = *(const f16x8*)&sm[1*P + arow];
    }
    f16x8 bh[4], bl[4];
#pragma unroll
    for (int nt = 0; nt < 4; nt++) {
      int brow = (wu*64 + nt*16 + lx16)*LSTR + kb;
      bh[nt] = *(const f16x8*)&sm[2*P + brow];
      bl[nt] = *(const f16x8*)&sm[3*P + brow];
    }
#pragma unroll
    for (int mt = 0; mt < 2; mt++)
#pragma unroll
      for (int nt = 0; nt < 4; nt++) {
        f32x4 a = acc[mt][nt];
        a = __builtin_amdgcn_mfma_f32_16x16x32_f16(ah[mt], bh[nt], a, 0, 0, 0);
        a = __builtin_amdgcn_mfma_f32_16x16x32_f16(ah[mt], bl[nt], a, 0, 0, 0);
        a = __builtin_amdgcn_mfma_f32_16x16x32_f16(al[mt], bh[nt], a, 0, 0, 0);
        acc[mt][nt] = a;
      }
  }
  float* Gs = (float*)sm;
  int btx = t & 15, bty = t >> 4;
#pragma unroll
  for (int h = 0; h < 2; h++) {
    __syncthreads();
    if ((wv >> 1) == h) {
      int rbase = (wv & 1) * 32;
#pragma unroll
      for (int mt = 0; mt < 2; mt++)
#pragma unroll
        for (int nt = 0; nt < 4; nt++)
#pragma unroll
          for (int i = 0; i < 4; i++)
            Gs[(rbase + mt*16 + quad*4 + i)*133 + wu*64 + nt*16 + lx16] = acc[mt][nt][i];
    }
    __syncthreads();
#pragma unroll
    for (int i = 0; i < 2; i++) {
      int px = bty*2 + i;
      int xm = refl(px-1), xp = refl(px+1);
#pragma unroll
      for (int jh = 0; jh < 2; jh++) {
        int ub = jh*64;
        float tmp[4];
#pragma unroll
        for (int j = 0; j < 4; j++) {
          int sx = btx*4 + j;
          int smm = refl(sx-1), sp = refl(sx+1);
          tmp[j] = Gs[xm*133 + ub + smm] + Gs[px*133 + ub + sx] + Gs[xp*133 + ub + sp];
        }
        *(float4*)&Hx[(size_t)(v0 + h*64 + px)*N_ + u0 + ub + btx*4] =
            make_float4(tmp[0], tmp[1], tmp[2], tmp[3]);
      }
    }
  }
}

// ---------------- y-diagonal blur of Hx + argmax ----------------
__global__ __launch_bounds__(256) void k_argmax(const float* Hx, const float* rnorm,
                                                int* idx, int b) {
  int p = blockIdx.x, t = threadIdx.x;
  int py = p >> 6, px = p & 63;
  size_t r0 = (size_t)(refl(py-1)*64 + px) * N_;
  size_t r1 = (size_t)p * N_;
  size_t r2 = (size_t)(refl(py+1)*64 + px) * N_;
  float bv = -1e30f; int bs = 0;
  for (int s = t; s < N_; s += 256) {
    int sy = s >> 6, sx = s & 63;
    int u0 = refl(sy-1)*64 + sx, u2 = refl(sy+1)*64 + sx;
    float acc = Hx[r0 + u0] + Hx[r1 + s] + Hx[r2 + u2];
    float sc = acc * rnorm[b*N_ + s];
    if (sc > bv) { bv = sc; bs = s; }
  }
  __shared__ float sv[256]; __shared__ int si[256];
  sv[t] = bv; si[t] = bs; __syncthreads();
  for (int off = 128; off > 0; off >>= 1) {
    if (t < off) {
      if (sv[t+off] > sv[t] || (sv[t+off] == sv[t] && si[t+off] < si[t])) {
        sv[t] = sv[t+off]; si[t] = si[t+off];
      }
    }
    __syncthreads();
  }
  if (!t) idx[b*N_ + p] = si[0];
}

// ---------------- deconv gather for batch b: recont_b[p][c] from fp16 pair ----------------
__global__ __launch_bounds__(256) void k_recon(const unsigned short* nsTh,
                                               const unsigned short* nsTl,
                                               const int* idx_b, float* recont_b) {
  int p = blockIdx.x, c = threadIdx.x;
  int py = p >> 6, px = p & 63;
  float acc = 0.f;
#pragma unroll
  for (int dy = 0; dy < 3; dy++)
#pragma unroll
    for (int dx = 0; dx < 3; dx++) {
      int q = refl(py+dy-1)*64 + refl(px+dx-1);
      int s = idx_b[q];
      int sy = s >> 6, sx = s & 63;
      size_t o = (size_t)(refl(sy+1-dy)*64 + refl(sx+1-dx))*C_ + c;
      acc += h2f(nsTh[o]) + h2f(nsTl[o]);
    }
  float dc = ((py==0||py==63)?2.f:3.f) * ((px==0||px==63)?2.f:3.f);
  recont_b[(size_t)p*C_ + c] = acc / dc;
}

// ---------------- coloring (MFMA): out = Ym·recont^T ----------------
__global__ __launch_bounds__(256) void k_color(const float* Yall, const float* recont_all,
                                               const float* cnrm, const float* means,
                                               float* out_all) {
  __shared__ unsigned short sm[4*64*LSTR];
  int b = blockIdx.z;
  const float* Ym = Yall + (size_t)(2+b)*65536;
  const float* recont = recont_all + (size_t)b*CN;   // [4096][256]
  const float* smean = means + (2+b)*C_;
  float* out = out_all + (size_t)b*CN;               // [256][4096]
  int m0 = blockIdx.y * 64;
  int n0 = blockIdx.x * 64;
  f32x4 acc[2][2];
  mm64_3term(sm, Ym, recont, m0, n0, acc);
  float scale = sqrtf(cnrm[2+b]);
  int t = threadIdx.x, lane = t & 63;
  int wv = (t >> 7) & 1, wu = (t >> 6) & 1, lx16 = lane & 15, quad = lane >> 4;
#pragma unroll
  for (int mt = 0; mt < 2; mt++)
#pragma unroll
    for (int nt = 0; nt < 2; nt++)
#pragma unroll
      for (int i = 0; i < 4; i++) {
        int r = m0 + wv*32 + mt*16 + quad*4 + i;
        int c = n0 + wu*32 + nt*16 + lx16;
        out[(size_t)r*N_ + c] = acc[mt][nt][i]*scale + smean[r];
      }
}

extern "C" void kernel_launch(void* const* d_in, const int* in_sizes, int n_in,
                              void* d_out, int out_size, void* d_ws, size_t ws_size,
                              hipStream_t stream) {
  const float* content = (const float*)d_in[0];
  const float* style   = (const float*)d_in[1];
  float* out = (float*)d_out;

  // workspace layout (floats); total ~102 MiB
  float* F = (float*)d_ws;
  float* means  = F + 0;         // 4*256
  float* cnrm   = F + 1024;      // 4
  float* Y      = F + 264192;    // NS buffers
  float* Z      = F + 526336;
  float* Y2     = F + 788480;
  float* Z2     = F + 1050624;
  float* T      = F + 1312768;
  float* ncreg  = F + 1574912;   // 16.8 MB region: outT (8 fp16 plane slots, 16 MB)
  float* nsreg  = F + 3672064;   // 16.8 MB region: xcT  (8 fp16 plane slots, 16 MB)
  float* recont = F + 7866368;   // 2*CN fp32
  float* ssq    = F + 9963520;   // 2*4096
  float* rnorm  = F + 9971712;   // 2*4096
  int*   idx    = (int*)(F + 9979904); // 2*4096
  float* Hx     = F + 9988096;   // 4096*4096

  // cov-phase aliases inside Hx (dead until k_gram at step 8):
  //  covsp = 4m x 2 planes x CN ushorts = 16.8 MB = 4.19M floats; covp after it.
  unsigned short* covsp = (unsigned short*)Hx;
  float* covp = Hx + 4194304;

  // fp16 plane arrays:
  //  xcT  [2m+p]: mean-subtracted transposed input planes (whiten input)
  //  outT [2m+p]: whitened transposed planes (gram/recon/ssq input); m=0,1 content b, 2,3 style b
  unsigned short* xcT  = (unsigned short*)nsreg;
  unsigned short* outT = (unsigned short*)ncreg;

  // 1-4. means, fused split, MFMA cov partials, trace, covred+nsinit
  k_mean<<<dim3(256,4), 256, 0, stream>>>(content, style, means);
  k_splitall<<<dim3(128,8,4), 256, 0, stream>>>(content, style, means, covsp, xcT);
  k_covmm<<<dim3(KSPLIT,4,4), 512, 0, stream>>>(covsp, covp);
  k_trace2<<<4, 256, 0, stream>>>(covp, means, cnrm);
  k_covred_init<<<dim3(256,4), 256, 0, stream>>>(covp, means, cnrm, Y, Z);
  // 5. NS iterations (MFMA)
  float *Ya = Y, *Za = Z, *Yb = Y2, *Zb = Z2;
  for (int it = 0; it < NS_ITERS; it++) {
    k_nsA<<<dim3(16,4), 256, 0, stream>>>(Za, Ya, T);
    k_nsB<<<dim3(16,4,2), 256, 0, stream>>>(Ya, Za, T, Yb, Zb);
    float* tmp;
    tmp = Ya; Ya = Yb; Yb = tmp;
    tmp = Za; Za = Zb; Zb = tmp;
  }
  // 6. whitening (MFMA) -> whitened transposed fp16 planes directly
  k_whitenT<<<dim3(64,4,4), 256, 0, stream>>>(xcT, Za, cnrm, outT);
  // 7. patch norms from planes
  k_ssq<<<dim3(16,2), 256, 0, stream>>>(outT, ssq);
  k_rnorm<<<dim3(16,2), 256, 0, stream>>>(ssq, rnorm);
  // 8. per batch: MFMA gram + x-blur -> y-blur+argmax -> recon
  for (int b = 0; b < 2; b++) {
    k_gram<<<dim3(32,32), 512, 0, stream>>>(outT + (size_t)(2*b)*CN,
                                            outT + (size_t)(2*b+1)*CN,
                                            outT + (size_t)(2*(2+b))*CN,
                                            outT + (size_t)(2*(2+b)+1)*CN, Hx);
    k_argmax<<<4096, 256, 0, stream>>>(Hx, rnorm, idx, b);
    k_recon<<<4096, 256, 0, stream>>>(outT + (size_t)(2*(2+b))*CN,
                                      outT + (size_t)(2*(2+b)+1)*CN,
                                      idx + (size_t)b*N_, recont + (size_t)b*CN);
  }
  // 9. coloring (MFMA)
  k_color<<<dim3(64,4,2), 256, 0, stream>>>(Ya, recont, cnrm, means, out);
}

// Round 7
// 351.757 us; speedup vs baseline: 1.4593x; 1.0694x over previous
//
#include <hip/hip_runtime.h>
#include <hip/hip_bf16.h>

#define C_ 256
#define N_ 4096
#define CN (C_*N_)
#define EPSF 1e-5f
#define NS_ITERS 6
#define KSPLIT 16  // split-K for MFMA cov partials
#define LSTR 40   // LDS row stride in ushort (80 B, 16B-aligned)

typedef _Float16 f16x8 __attribute__((ext_vector_type(8)));
typedef float f32x4 __attribute__((ext_vector_type(4)));

__device__ __forceinline__ int refl(int t) {
  return t < 0 ? -t : (t > 63 ? 126 - t : t);
}

// fp16 2-way split: v = h + l exact to ~2^-22 rel. Products hh+hl+lh drop only ll
// ~2^-22 rel — below the fp32 reference's own accumulation noise.
__device__ __forceinline__ unsigned short f2h(float x) {
  _Float16 h = (_Float16)x;
  return __builtin_bit_cast(unsigned short, h);
}
__device__ __forceinline__ float h2f(unsigned short u) {
  return (float)__builtin_bit_cast(_Float16, u);
}

// ---------------- shared MFMA helper: 64x64 out tile of A·B^T, K=256, fp32 in ----------------
// On-the-fly fp16 h/l split during staging; 3-term MFMA (hh+hl+lh). 256 thr = 4 waves.
__device__ __forceinline__ void mm64_3term(unsigned short* sm, const float* A, const float* B,
                                           int m0, int n0, f32x4 acc[2][2]) {
  const int P = 64*LSTR;
  int t = threadIdx.x;
  int lane = t & 63;
  int wv = (t >> 7) & 1, wu = (t >> 6) & 1;
  int lx16 = lane & 15, quad = lane >> 4;
  int srow = t >> 2, sseg = (t & 3) * 8;    // 256 thr = 64 rows x 4 segs of 8 floats
#pragma unroll
  for (int i = 0; i < 2; i++)
#pragma unroll
    for (int j = 0; j < 2; j++) acc[i][j] = (f32x4){0.f, 0.f, 0.f, 0.f};
  for (int k0 = 0; k0 < 256; k0 += 32) {
    __syncthreads();
    {
      const float* pa = &A[(size_t)(m0 + srow)*256 + k0 + sseg];
      const float* pb = &B[(size_t)(n0 + srow)*256 + k0 + sseg];
#pragma unroll
      for (int g = 0; g < 2; g++) {
        float4 va = *(const float4*)(pa + g*4);
        float4 vb = *(const float4*)(pb + g*4);
        float fa[4] = {va.x, va.y, va.z, va.w};
        float fb[4] = {vb.x, vb.y, vb.z, vb.w};
        unsigned short ha[4], la[4], hb[4], lb[4];
#pragma unroll
        for (int j = 0; j < 4; j++) {
          unsigned short h = f2h(fa[j]); ha[j] = h; la[j] = f2h(fa[j] - h2f(h));
          h = f2h(fb[j]); hb[j] = h; lb[j] = f2h(fb[j] - h2f(h));
        }
        int lo_ = srow*LSTR + sseg + g*4;
        *(ushort4*)&sm[0*P + lo_] = make_ushort4(ha[0], ha[1], ha[2], ha[3]);
        *(ushort4*)&sm[1*P + lo_] = make_ushort4(la[0], la[1], la[2], la[3]);
        *(ushort4*)&sm[2*P + lo_] = make_ushort4(hb[0], hb[1], hb[2], hb[3]);
        *(ushort4*)&sm[3*P + lo_] = make_ushort4(lb[0], lb[1], lb[2], lb[3]);
      }
    }
    __syncthreads();
    f16x8 ah[2], al[2], bh[2], bl[2];
#pragma unroll
    for (int mt = 0; mt < 2; mt++) {
      int arow = (wv*32 + mt*16 + lx16)*LSTR + quad*8;
      ah[mt] = *(const f16x8*)&sm[0*P + arow];
      al[mt] = *(const f16x8*)&sm[1*P + arow];
    }
#pragma unroll
    for (int nt = 0; nt < 2; nt++) {
      int brow = (wu*32 + nt*16 + lx16)*LSTR + quad*8;
      bh[nt] = *(const f16x8*)&sm[2*P + brow];
      bl[nt] = *(const f16x8*)&sm[3*P + brow];
    }
#pragma unroll
    for (int mt = 0; mt < 2; mt++)
#pragma unroll
      for (int nt = 0; nt < 2; nt++) {
        f32x4 a = acc[mt][nt];
        a = __builtin_amdgcn_mfma_f32_16x16x32_f16(ah[mt], bh[nt], a, 0, 0, 0);
        a = __builtin_amdgcn_mfma_f32_16x16x32_f16(ah[mt], bl[nt], a, 0, 0, 0);
        a = __builtin_amdgcn_mfma_f32_16x16x32_f16(al[mt], bh[nt], a, 0, 0, 0);
        acc[mt][nt] = a;
      }
  }
}

// ---------------- mm32: 32x32 out tile of A·B^T, K=256, fp32 in (NS parallelism) ----------
// 256 thr = 4 waves, each wave one 16x16 tile (wv,wu). LDS 10240 B.
__device__ __forceinline__ f32x4 mm32_3term(unsigned short* sm, const float* A, const float* B,
                                            int m0, int n0) {
  const int P = 32*LSTR;
  int t = threadIdx.x, lane = t & 63;
  int w = t >> 6, wv = w >> 1, wu = w & 1;
  int lx16 = lane & 15, quad = lane >> 4;
  int mat = t >> 7, srow = (t >> 2) & 31, sseg = (t & 3) * 8;
  const float* S = mat ? B : A;
  int rb = mat ? n0 : m0;
  int base0 = mat ? 2*P : 0;
  f32x4 acc = (f32x4){0.f, 0.f, 0.f, 0.f};
  for (int k0 = 0; k0 < 256; k0 += 32) {
    __syncthreads();
    {
      const float* p = &S[(size_t)(rb + srow)*256 + k0 + sseg];
      int lo_ = srow*LSTR + sseg;
#pragma unroll
      for (int g = 0; g < 2; g++) {
        float4 v = *(const float4*)(p + g*4);
        float f[4] = {v.x, v.y, v.z, v.w};
        unsigned short hh[4], ll[4];
#pragma unroll
        for (int j = 0; j < 4; j++) {
          unsigned short h = f2h(f[j]); hh[j] = h; ll[j] = f2h(f[j] - h2f(h));
        }
        *(ushort4*)&sm[base0 + lo_ + g*4]     = make_ushort4(hh[0], hh[1], hh[2], hh[3]);
        *(ushort4*)&sm[base0 + P + lo_ + g*4] = make_ushort4(ll[0], ll[1], ll[2], ll[3]);
      }
    }
    __syncthreads();
    int arow = (wv*16 + lx16)*LSTR + quad*8;
    int brow = (wu*16 + lx16)*LSTR + quad*8;
    f16x8 ah = *(const f16x8*)&sm[0*P + arow];
    f16x8 al = *(const f16x8*)&sm[1*P + arow];
    f16x8 bh = *(const f16x8*)&sm[2*P + brow];
    f16x8 bl = *(const f16x8*)&sm[3*P + brow];
    acc = __builtin_amdgcn_mfma_f32_16x16x32_f16(ah, bh, acc, 0, 0, 0);
    acc = __builtin_amdgcn_mfma_f32_16x16x32_f16(ah, bl, acc, 0, 0, 0);
    acc = __builtin_amdgcn_mfma_f32_16x16x32_f16(al, bh, acc, 0, 0, 0);
  }
  return acc;
}

// ---------------- means ----------------
__global__ __launch_bounds__(256) void k_mean(const float* content, const float* style,
                                              float* means) {
  int c = blockIdx.x, m = blockIdx.y, t = threadIdx.x;
  const float* x = (m < 2 ? content : style) + (size_t)(m & 1) * CN + (size_t)c * N_;
  float s = 0.f;
  for (int i = t; i < N_; i += 256) s += x[i];
  __shared__ float red[256];
  red[t] = s; __syncthreads();
  for (int off = 128; off > 0; off >>= 1) { if (t < off) red[t] += red[t + off]; __syncthreads(); }
  if (t == 0) means[m * C_ + c] = red[0] * (1.f / N_);
}

// ---------------- fused split: raw [c][n] planes for cov + mean-sub transposed [v][c] planes ----
__global__ __launch_bounds__(256) void k_splitall(const float* content, const float* style,
                                                  const float* means,
                                                  unsigned short* covsp, unsigned short* xcT) {
  int m = blockIdx.z;
  const float* x = (m < 2 ? content : style) + (size_t)(m & 1) * CN;
  int u0 = blockIdx.x * 32, c0 = blockIdx.y * 32;
  unsigned short* ch_ = covsp + (size_t)(2*m+0)*CN;
  unsigned short* cl_ = covsp + (size_t)(2*m+1)*CN;
  unsigned short* th_ = xcT + (size_t)(2*m+0)*CN;
  unsigned short* tl_ = xcT + (size_t)(2*m+1)*CN;
  __shared__ float tile[32][33];
  int t = threadIdx.x;
  {
    int cc = t >> 3, uu4 = (t & 7) * 4;
    float4 v = *(const float4*)&x[(size_t)(c0+cc)*N_ + u0 + uu4];
    float f[4] = {v.x, v.y, v.z, v.w};
    unsigned short h[4], lo[4];
#pragma unroll
    for (int j = 0; j < 4; j++) {
      unsigned short hh = f2h(f[j]);
      h[j] = hh; lo[j] = f2h(f[j] - h2f(hh));
      tile[cc][uu4+j] = f[j];
    }
    size_t o = (size_t)(c0+cc)*N_ + u0 + uu4;
    *(ushort4*)&ch_[o] = make_ushort4(h[0], h[1], h[2], h[3]);
    *(ushort4*)&cl_[o] = make_ushort4(lo[0], lo[1], lo[2], lo[3]);
  }
  __syncthreads();
  {
    int uu = t >> 3, cc4 = (t & 7) * 4;
    unsigned short h[4], lo[4];
#pragma unroll
    for (int j = 0; j < 4; j++) {
      float v = tile[cc4+j][uu] - means[m*C_ + c0 + cc4 + j];
      unsigned short hh = f2h(v);
      h[j] = hh; lo[j] = f2h(v - h2f(hh));
    }
    size_t o = (size_t)(u0+uu)*C_ + c0 + cc4;
    *(ushort4*)&th_[o] = make_ushort4(h[0], h[1], h[2], h[3]);
    *(ushort4*)&tl_[o] = make_ushort4(lo[0], lo[1], lo[2], lo[3]);
  }
}

// ---------------- covariance raw sums via 3-term fp16 MFMA, split-K ----------------
__global__ __launch_bounds__(512) void k_covmm(const unsigned short* sp, float* covp) {
  __shared__ unsigned short sm[4*128*LSTR];   // 40960 B
  const int P = 128*LSTR;
  int t = threadIdx.x;
  int kc = blockIdx.x, m = blockIdx.z;
  int ti = blockIdx.y >> 1, tj = blockIdx.y & 1;
  const unsigned short* Xh = sp + (size_t)m * 2 * (size_t)CN;
  const unsigned short* Xl = Xh + CN;
  int v0 = ti * 128, u0 = tj * 128;
  int wave = t >> 6, lane = t & 63;
  int wv = wave >> 1, wu = wave & 1;
  int lx16 = lane & 15, quad = lane >> 4;
  int srow = t >> 2, sseg = (t & 3) * 8;
  f32x4 acc[2][4];
#pragma unroll
  for (int i = 0; i < 2; i++)
#pragma unroll
    for (int j = 0; j < 4; j++) acc[i][j] = (f32x4){0.f, 0.f, 0.f, 0.f};

  int kbeg = kc * (N_ / KSPLIT), kend = kbeg + (N_ / KSPLIT);
  for (int k0 = kbeg; k0 < kend; k0 += 32) {
    __syncthreads();
    {
      size_t goA = (size_t)(v0 + srow) * N_ + k0 + sseg;
      size_t goB = (size_t)(u0 + srow) * N_ + k0 + sseg;
      int lo_ = srow * LSTR + sseg;
      *(float4*)&sm[0*P + lo_] = *(const float4*)&Xh[goA];
      *(float4*)&sm[1*P + lo_] = *(const float4*)&Xl[goA];
      *(float4*)&sm[2*P + lo_] = *(const float4*)&Xh[goB];
      *(float4*)&sm[3*P + lo_] = *(const float4*)&Xl[goB];
    }
    __syncthreads();
#pragma unroll
    for (int mt = 0; mt < 2; mt++) {
      int arow = (wv*32 + mt*16 + lx16)*LSTR + quad*8;
      f16x8 ah = *(const f16x8*)&sm[0*P + arow];
      f16x8 al = *(const f16x8*)&sm[1*P + arow];
#pragma unroll
      for (int nt = 0; nt < 4; nt++) {
        int brow = (wu*64 + nt*16 + lx16)*LSTR + quad*8;
        f16x8 bh = *(const f16x8*)&sm[2*P + brow];
        f16x8 bl = *(const f16x8*)&sm[3*P + brow];
        f32x4 a = acc[mt][nt];
        a = __builtin_amdgcn_mfma_f32_16x16x32_f16(ah, bh, a, 0, 0, 0);
        a = __builtin_amdgcn_mfma_f32_16x16x32_f16(ah, bl, a, 0, 0, 0);
        a = __builtin_amdgcn_mfma_f32_16x16x32_f16(al, bh, a, 0, 0, 0);
        acc[mt][nt] = a;
      }
    }
  }
  float* O = covp + ((size_t)kc*4 + m) * 65536;
#pragma unroll
  for (int mt = 0; mt < 2; mt++)
#pragma unroll
    for (int nt = 0; nt < 4; nt++)
#pragma unroll
      for (int i = 0; i < 4; i++)
        O[(size_t)(v0 + wv*32 + mt*16 + quad*4 + i)*C_ + (u0 + wu*64 + nt*16 + lx16)] =
            acc[mt][nt][i];
}

// ---------------- trace from partials -> cnrm = (tr/256)*1.3 ----------------
__global__ __launch_bounds__(256) void k_trace2(const float* covp, const float* means,
                                                float* cnrm) {
  int m = blockIdx.x, t = threadIdx.x;
  float s = 0.f;
#pragma unroll
  for (int kc = 0; kc < KSPLIT; kc++)
    s += covp[((size_t)kc*4 + m)*65536 + (size_t)t*257];
  float mi = means[m*C_ + t];
  float d = (s - (float)N_*mi*mi) * (1.f/(float)(N_-1));
  __shared__ float red[256];
  red[t] = d; __syncthreads();
  for (int off = 128; off > 0; off >>= 1) { if (t < off) red[t] += red[t + off]; __syncthreads(); }
  if (!t) cnrm[m] = red[0] * (1.3f/256.f);
}

// ---------------- merged covred + nsinit ----------------
__global__ __launch_bounds__(256) void k_covred_init(const float* covp, const float* means,
                                                     const float* cnrm, float* Y, float* Z) {
  int i = blockIdx.x, m = blockIdx.y, j = threadIdx.x;
  float s = 0.f;
#pragma unroll
  for (int kc = 0; kc < KSPLIT; kc++)
    s += covp[((size_t)kc*4 + m)*65536 + (size_t)i*C_ + j];
  float mi = means[m*C_ + i], mj = means[m*C_ + j];
  float cv = (s - (float)N_*mi*mj) * (1.f/(float)(N_-1));
  size_t o = (size_t)m*65536 + (size_t)i*C_ + j;
  Y[o] = cv / cnrm[m];
  Z[o] = (i == j) ? 1.f : 0.f;
}

// ---------------- NS phase A (MFMA, 32x32 tiles): T = 3I - Z·Y^T ----------------
// NS iterates are polynomials in Y0 (Z0=I) -> symmetric & commuting, so Z·Y^T == Z·Y.
__global__ __launch_bounds__(256) void k_nsA(const float* Zin, const float* Yin, float* T) {
  __shared__ unsigned short sm[4*32*LSTR];   // 10240 B
  int m = blockIdx.y;
  int m0 = (blockIdx.x >> 3) * 32, n0 = (blockIdx.x & 7) * 32;
  const float* A = Zin + (size_t)m*65536;
  const float* B = Yin + (size_t)m*65536;
  float* O = T + (size_t)m*65536;
  f32x4 acc = mm32_3term(sm, A, B, m0, n0);
  int t = threadIdx.x, lane = t & 63;
  int w = t >> 6, wv = w >> 1, wu = w & 1;
  int lx16 = lane & 15, quad = lane >> 4;
#pragma unroll
  for (int i = 0; i < 4; i++) {
    int r = m0 + wv*16 + quad*4 + i;
    int c = n0 + wu*16 + lx16;
    float v = acc[i];
    O[(size_t)r*256 + c] = (r == c) ? 3.f - v : -v;
  }
}

// ---------------- NS phase B (MFMA, 32x32 tiles) ----------------
__global__ __launch_bounds__(256) void k_nsB(const float* Yin, const float* Zin, const float* T,
                                             float* Yout, float* Zout) {
  __shared__ unsigned short sm[4*32*LSTR];
  int m = blockIdx.y, z = blockIdx.z;
  const float* A = (z == 0 ? Yin : Zin) + (size_t)m*65536;
  const float* B = T + (size_t)m*65536;
  float* O = (z == 0 ? Yout : Zout) + (size_t)m*65536;
  int m0 = (blockIdx.x >> 3) * 32, n0 = (blockIdx.x & 7) * 32;
  f32x4 acc = mm32_3term(sm, A, B, m0, n0);
  int t = threadIdx.x, lane = t & 63;
  int w = t >> 6, wv = w >> 1, wu = w & 1;
  int lx16 = lane & 15, quad = lane >> 4;
#pragma unroll
  for (int i = 0; i < 4; i++) {
    int r = m0 + wv*16 + quad*4 + i;
    int c = n0 + wu*16 + lx16;
    O[(size_t)r*256 + c] = 0.5f * acc[i];
  }
}

// ---------------- whiten via MFMA, writing whitened TRANSPOSED fp16 planes directly ----------
__global__ __launch_bounds__(256) void k_whitenT(const unsigned short* xcT, const float* Zall,
                                                 const float* cnrm, unsigned short* outT) {
  __shared__ unsigned short sm[4*64*LSTR];   // 20480 B; epilogue Th/Tl [64][72] unioned
  const int P = 64*LSTR;
  int m = blockIdx.z;
  int v0 = blockIdx.x * 64, c0 = blockIdx.y * 64;
  const float* Zm = Zall + (size_t)m*65536;
  const unsigned short* Bh_g = xcT + (size_t)(2*m+0)*CN;
  const unsigned short* Bl_g = xcT + (size_t)(2*m+1)*CN;
  unsigned short* Oh = outT + (size_t)(2*m+0)*CN;
  unsigned short* Ol = outT + (size_t)(2*m+1)*CN;
  int t = threadIdx.x, lane = t & 63;
  int wv = (t >> 7) & 1, wu = (t >> 6) & 1;
  int lx16 = lane & 15, quad = lane >> 4;
  int srow = t >> 2, sseg = (t & 3) * 8;
  f32x4 acc[2][2];
#pragma unroll
  for (int i = 0; i < 2; i++)
#pragma unroll
    for (int j = 0; j < 2; j++) acc[i][j] = (f32x4){0.f, 0.f, 0.f, 0.f};
  for (int k0 = 0; k0 < 256; k0 += 32) {
    __syncthreads();
    {
      const float* pa = &Zm[(size_t)(c0 + srow)*256 + k0 + sseg];
      int lo_ = srow*LSTR + sseg;
#pragma unroll
      for (int g = 0; g < 2; g++) {
        float4 va = *(const float4*)(pa + g*4);
        float fa[4] = {va.x, va.y, va.z, va.w};
        unsigned short ha[4], la[4];
#pragma unroll
        for (int j = 0; j < 4; j++) {
          unsigned short h = f2h(fa[j]); ha[j] = h; la[j] = f2h(fa[j] - h2f(h));
        }
        *(ushort4*)&sm[0*P + lo_ + g*4] = make_ushort4(ha[0], ha[1], ha[2], ha[3]);
        *(ushort4*)&sm[1*P + lo_ + g*4] = make_ushort4(la[0], la[1], la[2], la[3]);
      }
      size_t gb = (size_t)(v0 + srow)*C_ + k0 + sseg;
      *(float4*)&sm[2*P + lo_] = *(const float4*)&Bh_g[gb];
      *(float4*)&sm[3*P + lo_] = *(const float4*)&Bl_g[gb];
    }
    __syncthreads();
    f16x8 ah[2], al[2], bh[2], bl[2];
#pragma unroll
    for (int mt = 0; mt < 2; mt++) {
      int arow = (wv*32 + mt*16 + lx16)*LSTR + quad*8;
      ah[mt] = *(const f16x8*)&sm[0*P + arow];
      al[mt] = *(const f16x8*)&sm[1*P + arow];
    }
#pragma unroll
    for (int nt = 0; nt < 2; nt++) {
      int brow = (wu*32 + nt*16 + lx16)*LSTR + quad*8;
      bh[nt] = *(const f16x8*)&sm[2*P + brow];
      bl[nt] = *(const f16x8*)&sm[3*P + brow];
    }
#pragma unroll
    for (int mt = 0; mt < 2; mt++)
#pragma unroll
      for (int nt = 0; nt < 2; nt++) {
        f32x4 a = acc[mt][nt];
        a = __builtin_amdgcn_mfma_f32_16x16x32_f16(ah[mt], bh[nt], a, 0, 0, 0);
        a = __builtin_amdgcn_mfma_f32_16x16x32_f16(ah[mt], bl[nt], a, 0, 0, 0);
        a = __builtin_amdgcn_mfma_f32_16x16x32_f16(al[mt], bh[nt], a, 0, 0, 0);
        acc[mt][nt] = a;
      }
  }
  float scale = 1.0f / sqrtf(cnrm[m]);
  __syncthreads();
  unsigned short* Th = sm;             // [64][72]
  unsigned short* Tl = sm + 64*72;
#pragma unroll
  for (int mt = 0; mt < 2; mt++)
#pragma unroll
    for (int nt = 0; nt < 2; nt++)
#pragma unroll
      for (int i = 0; i < 4; i++) {
        int chl = wv*32 + mt*16 + quad*4 + i;
        int vl  = wu*32 + nt*16 + lx16;
        float w = acc[mt][nt][i] * scale;
        unsigned short h = f2h(w);
        unsigned short l = f2h(w - h2f(h));
        Th[vl*72 + chl] = h;
        Tl[vl*72 + chl] = l;
      }
  __syncthreads();
  int vr = t >> 2, cs = (t & 3) * 16;
  size_t go = (size_t)(v0 + vr)*C_ + c0 + cs;
  *(float4*)&Oh[go]     = *(float4*)&Th[vr*72 + cs];
  *(float4*)&Oh[go + 8] = *(float4*)&Th[vr*72 + cs + 8];
  *(float4*)&Ol[go]     = *(float4*)&Tl[vr*72 + cs];
  *(float4*)&Ol[go + 8] = *(float4*)&Tl[vr*72 + cs + 8];
}

// ---------------- per-pixel channel sum-of-squares from whitened planes ----------------
__global__ __launch_bounds__(256) void k_ssq(const unsigned short* outT, float* ssq) {
  int b = blockIdx.y; int p = blockIdx.x * 256 + threadIdx.x;
  const unsigned short* h = outT + (size_t)(2*(2+b))*CN + (size_t)p*C_;
  const unsigned short* l = h + CN;
  float acc = 0.f;
  for (int c = 0; c < C_; c += 4) {
    ushort4 hv = *(const ushort4*)&h[c];
    ushort4 lv = *(const ushort4*)&l[c];
    float v0 = h2f(hv.x) + h2f(lv.x);
    float v1 = h2f(hv.y) + h2f(lv.y);
    float v2 = h2f(hv.z) + h2f(lv.z);
    float v3 = h2f(hv.w) + h2f(lv.w);
    acc += v0*v0 + v1*v1 + v2*v2 + v3*v3;
  }
  ssq[b*N_ + p] = acc;
}

// ---------------- patch reciprocal norms ----------------
__global__ __launch_bounds__(256) void k_rnorm(const float* ssq, float* rnorm) {
  int b = blockIdx.y; int s = blockIdx.x * 256 + threadIdx.x;
  int sy = s >> 6, sx = s & 63;
  float sum = 0.f;
#pragma unroll
  for (int ky = 0; ky < 3; ky++)
#pragma unroll
    for (int kx = 0; kx < 3; kx++)
      sum += ssq[b*N_ + refl(sy+ky-1)*64 + refl(sx+kx-1)];
  rnorm[b*N_ + s] = 1.f / (sqrtf(sum) + EPSF);
}

// ---------------- Gram via 2-way-split fp16 MFMA + fused x-blur ----------------
// Epilogue px remap (px = bty + 32*i, was bty*2+i): blur-read bank = (5*bty' + 4*btx) mod 32
// covers all residues mod 4 -> exact 2-way (free), vs old (10*bty'+4*btx) = even-only 4-way.
__global__ __launch_bounds__(512) void k_gram(const unsigned short* Ah_g, const unsigned short* Al_g,
                                              const unsigned short* Bh_g, const unsigned short* Bl_g,
                                              float* Hx) {
  __shared__ unsigned short sm[4*128*LSTR];  // 40960 B; epilogue Gs[64][133] fp32 unioned
  const int P = 128*LSTR;
  int t = threadIdx.x;
  int v0 = blockIdx.y * 128, u0 = blockIdx.x * 128;
  int wave = t >> 6, lane = t & 63;
  int wv = wave >> 1, wu = wave & 1;
  int lx16 = lane & 15, quad = lane >> 4;
  int srow = t >> 2, sseg = (t & 3) * 8;
  f32x4 acc[2][4];
#pragma unroll
  for (int i = 0; i < 2; i++)
#pragma unroll
    for (int j = 0; j < 4; j++) acc[i][j] = (f32x4){0.f, 0.f, 0.f, 0.f};

  for (int k0 = 0; k0 < 256; k0 += 32) {
    __syncthreads();
    {
      size_t goA = (size_t)(v0 + srow)*C_ + k0 + sseg;
      size_t goB = (size_t)(u0 + srow)*C_ + k0 + sseg;
      int lo_ = srow*LSTR + sseg;
      *(float4*)&sm[0*P + lo_] = *(const float4*)&Ah_g[goA];
      *(float4*)&sm[1*P + lo_] = *(const float4*)&Al_g[goA];
      *(float4*)&sm[2*P + lo_] = *(const float4*)&Bh_g[goB];
      *(float4*)&sm[3*P + lo_] = *(const float4*)&Bl_g[goB];
    }
    __syncthreads();
    int kb = quad*8;
    f16x8 ah[2], al[2];
#pragma unroll
    for (int mt = 0; mt < 2; mt++) {
      int arow = (wv*32 + mt*16 + lx16)*LSTR + kb;
      ah[mt] = *(const f16x8*)&sm[0*P + arow];
      al[mt] = *(const f16x8*)&sm[1*P + arow];
    }
    f16x8 bh[4], bl[4];
#pragma unroll
    for (int nt = 0; nt < 4; nt++) {
      int brow = (wu*64 + nt*16 + lx16)*LSTR + kb;
      bh[nt] = *(const f16x8*)&sm[2*P + brow];
      bl[nt] = *(const f16x8*)&sm[3*P + brow];
    }
#pragma unroll
    for (int mt = 0; mt < 2; mt++)
#pragma unroll
      for (int nt = 0; nt < 4; nt++) {
        f32x4 a = acc[mt][nt];
        a = __builtin_amdgcn_mfma_f32_16x16x32_f16(ah[mt], bh[nt], a, 0, 0, 0);
        a = __builtin_amdgcn_mfma_f32_16x16x32_f16(ah[mt], bl[nt], a, 0, 0, 0);
        a = __builtin_amdgcn_mfma_f32_16x16x32_f16(al[mt], bh[nt], a, 0, 0, 0);
        acc[mt][nt] = a;
      }
  }
  float* Gs = (float*)sm;
  int btx = t & 15, bty = t >> 4;
#pragma unroll
  for (int h = 0; h < 2; h++) {
    __syncthreads();
    if ((wv >> 1) == h) {
      int rbase = (wv & 1) * 32;
#pragma unroll
      for (int mt = 0; mt < 2; mt++)
#pragma unroll
        for (int nt = 0; nt < 4; nt++)
#pragma unroll
          for (int i = 0; i < 4; i++)
            Gs[(rbase + mt*16 + quad*4 + i)*133 + wu*64 + nt*16 + lx16] = acc[mt][nt][i];
    }
    __syncthreads();
#pragma unroll
    for (int i = 0; i < 2; i++) {
      int px = bty + 32*i;                 // bank-spread remap
      int xm = refl(px-1), xp = refl(px+1);
#pragma unroll
      for (int jh = 0; jh < 2; jh++) {
        int ub = jh*64;
        float tmp[4];
#pragma unroll
        for (int j = 0; j < 4; j++) {
          int sx = btx*4 + j;
          int smm = refl(sx-1), sp = refl(sx+1);
          tmp[j] = Gs[xm*133 + ub + smm] + Gs[px*133 + ub + sx] + Gs[xp*133 + ub + sp];
        }
        *(float4*)&Hx[(size_t)(v0 + h*64 + px)*N_ + u0 + ub + btx*4] =
            make_float4(tmp[0], tmp[1], tmp[2], tmp[3]);
      }
    }
  }
}

// ---------------- y-diagonal blur of Hx + argmax (paired py: 4 rows per 2 outputs) --------
__global__ __launch_bounds__(256) void k_argmax(const float* Hx, const float* rnorm,
                                                int* idx, int b) {
  int blk = blockIdx.x, t = threadIdx.x;
  int q = blk >> 6, px = blk & 63;
  int py0 = 2*q, py1 = 2*q + 1;
  size_t rm = (size_t)(refl(py0-1)*64 + px) * N_;
  size_t r0 = (size_t)(py0*64 + px) * N_;
  size_t r1 = (size_t)(py1*64 + px) * N_;
  size_t rp = (size_t)(refl(py1+1)*64 + px) * N_;
  float bv0 = -1e30f, bv1 = -1e30f; int bs0 = 0, bs1 = 0;
  for (int s = t; s < N_; s += 256) {
    int sy = s >> 6, sx = s & 63;
    int u0 = refl(sy-1)*64 + sx, u2 = refl(sy+1)*64 + sx;
    float rn = rnorm[b*N_ + s];
    float a0 = Hx[rm + u0] + Hx[r0 + s] + Hx[r1 + u2];
    float a1 = Hx[r0 + u0] + Hx[r1 + s] + Hx[rp + u2];
    float sc0 = a0 * rn, sc1 = a1 * rn;
    if (sc0 > bv0) { bv0 = sc0; bs0 = s; }
    if (sc1 > bv1) { bv1 = sc1; bs1 = s; }
  }
  __shared__ float sv[256]; __shared__ int si[256];
  sv[t] = bv0; si[t] = bs0; __syncthreads();
  for (int off = 128; off > 0; off >>= 1) {
    if (t < off) {
      if (sv[t+off] > sv[t] || (sv[t+off] == sv[t] && si[t+off] < si[t])) {
        sv[t] = sv[t+off]; si[t] = si[t+off];
      }
    }
    __syncthreads();
  }
  if (!t) idx[b*N_ + py0*64 + px] = si[0];
  __syncthreads();
  sv[t] = bv1; si[t] = bs1; __syncthreads();
  for (int off = 128; off > 0; off >>= 1) {
    if (t < off) {
      if (sv[t+off] > sv[t] || (sv[t+off] == sv[t] && si[t+off] < si[t])) {
        sv[t] = sv[t+off]; si[t] = si[t+off];
      }
    }
    __syncthreads();
  }
  if (!t) idx[b*N_ + py1*64 + px] = si[0];
}

// ---------------- deconv gather for batch b: recont_b[p][c] from fp16 pair ----------------
__global__ __launch_bounds__(256) void k_recon(const unsigned short* nsTh,
                                               const unsigned short* nsTl,
                                               const int* idx_b, float* recont_b) {
  int p = blockIdx.x, c = threadIdx.x;
  int py = p >> 6, px = p & 63;
  float acc = 0.f;
#pragma unroll
  for (int dy = 0; dy < 3; dy++)
#pragma unroll
    for (int dx = 0; dx < 3; dx++) {
      int q = refl(py+dy-1)*64 + refl(px+dx-1);
      int s = idx_b[q];
      int sy = s >> 6, sx = s & 63;
      size_t o = (size_t)(refl(sy+1-dy)*64 + refl(sx+1-dx))*C_ + c;
      acc += h2f(nsTh[o]) + h2f(nsTl[o]);
    }
  float dc = ((py==0||py==63)?2.f:3.f) * ((px==0||px==63)?2.f:3.f);
  recont_b[(size_t)p*C_ + c] = acc / dc;
}

// ---------------- coloring (MFMA): out = Ym·recont^T ----------------
__global__ __launch_bounds__(256) void k_color(const float* Yall, const float* recont_all,
                                               const float* cnrm, const float* means,
                                               float* out_all) {
  __shared__ unsigned short sm[4*64*LSTR];
  int b = blockIdx.z;
  const float* Ym = Yall + (size_t)(2+b)*65536;
  const float* recont = recont_all + (size_t)b*CN;   // [4096][256]
  const float* smean = means + (2+b)*C_;
  float* out = out_all + (size_t)b*CN;               // [256][4096]
  int m0 = blockIdx.y * 64;
  int n0 = blockIdx.x * 64;
  f32x4 acc[2][2];
  mm64_3term(sm, Ym, recont, m0, n0, acc);
  float scale = sqrtf(cnrm[2+b]);
  int t = threadIdx.x, lane = t & 63;
  int wv = (t >> 7) & 1, wu = (t >> 6) & 1, lx16 = lane & 15, quad = lane >> 4;
#pragma unroll
  for (int mt = 0; mt < 2; mt++)
#pragma unroll
    for (int nt = 0; nt < 2; nt++)
#pragma unroll
      for (int i = 0; i < 4; i++) {
        int r = m0 + wv*32 + mt*16 + quad*4 + i;
        int c = n0 + wu*32 + nt*16 + lx16;
        out[(size_t)r*N_ + c] = acc[mt][nt][i]*scale + smean[r];
      }
}

extern "C" void kernel_launch(void* const* d_in, const int* in_sizes, int n_in,
                              void* d_out, int out_size, void* d_ws, size_t ws_size,
                              hipStream_t stream) {
  const float* content = (const float*)d_in[0];
  const float* style   = (const float*)d_in[1];
  float* out = (float*)d_out;

  // workspace layout (floats); total ~102 MiB
  float* F = (float*)d_ws;
  float* means  = F + 0;         // 4*256
  float* cnrm   = F + 1024;      // 4
  float* Y      = F + 264192;    // NS buffers
  float* Z      = F + 526336;
  float* Y2     = F + 788480;
  float* Z2     = F + 1050624;
  float* T      = F + 1312768;
  float* ncreg  = F + 1574912;   // outT (8 fp16 plane slots, 16 MB)
  float* nsreg  = F + 3672064;   // xcT  (8 fp16 plane slots, 16 MB)
  float* recont = F + 7866368;   // 2*CN fp32
  float* ssq    = F + 9963520;   // 2*4096
  float* rnorm  = F + 9971712;   // 2*4096
  int*   idx    = (int*)(F + 9979904); // 2*4096
  float* Hx     = F + 9988096;   // 4096*4096

  // cov-phase aliases inside Hx (dead until k_gram at step 8)
  unsigned short* covsp = (unsigned short*)Hx;
  float* covp = Hx + 4194304;

  unsigned short* xcT  = (unsigned short*)nsreg;
  unsigned short* outT = (unsigned short*)ncreg;

  // 1-4. means, fused split, MFMA cov partials, trace, covred+nsinit
  k_mean<<<dim3(256,4), 256, 0, stream>>>(content, style, means);
  k_splitall<<<dim3(128,8,4), 256, 0, stream>>>(content, style, means, covsp, xcT);
  k_covmm<<<dim3(KSPLIT,4,4), 512, 0, stream>>>(covsp, covp);
  k_trace2<<<4, 256, 0, stream>>>(covp, means, cnrm);
  k_covred_init<<<dim3(256,4), 256, 0, stream>>>(covp, means, cnrm, Y, Z);
  // 5. NS iterations (MFMA, 32x32 tiles for parallelism)
  float *Ya = Y, *Za = Z, *Yb = Y2, *Zb = Z2;
  for (int it = 0; it < NS_ITERS; it++) {
    k_nsA<<<dim3(64,4), 256, 0, stream>>>(Za, Ya, T);
    k_nsB<<<dim3(64,4,2), 256, 0, stream>>>(Ya, Za, T, Yb, Zb);
    float* tmp;
    tmp = Ya; Ya = Yb; Yb = tmp;
    tmp = Za; Za = Zb; Zb = tmp;
  }
  // 6. whitening (MFMA) -> whitened transposed fp16 planes directly
  k_whitenT<<<dim3(64,4,4), 256, 0, stream>>>(xcT, Za, cnrm, outT);
  // 7. patch norms from planes
  k_ssq<<<dim3(16,2), 256, 0, stream>>>(outT, ssq);
  k_rnorm<<<dim3(16,2), 256, 0, stream>>>(ssq, rnorm);
  // 8. per batch: MFMA gram + x-blur -> paired y-blur+argmax -> recon
  for (int b = 0; b < 2; b++) {
    k_gram<<<dim3(32,32), 512, 0, stream>>>(outT + (size_t)(2*b)*CN,
                                            outT + (size_t)(2*b+1)*CN,
                                            outT + (size_t)(2*(2+b))*CN,
                                            outT + (size_t)(2*(2+b)+1)*CN, Hx);
    k_argmax<<<2048, 256, 0, stream>>>(Hx, rnorm, idx, b);
    k_recon<<<4096, 256, 0, stream>>>(outT + (size_t)(2*(2+b))*CN,
                                      outT + (size_t)(2*(2+b)+1)*CN,
                                      idx + (size_t)b*N_, recont + (size_t)b*CN);
  }
  // 9. coloring (MFMA)
  k_color<<<dim3(64,4,2), 256, 0, stream>>>(Ya, recont, cnrm, means, out);
}